// Round 5
// baseline (7223.174 us; speedup 1.0000x reference)
//
#include <hip/hip_runtime.h>
#include <hip/hip_bf16.h>
#include <cstdint>
#include <math.h>

// ---------------------------------------------------------------------------
// AdaptiveMCTSReasoner  B=16, S=1024, H=1024, MAX_SIMS=100, K_FOCUS=3
// Round 5: round-4 structure, but random bits generated in JAX
// THREEFRY-PARTITIONABLE mode (default since jax 0.4.36):
//   bits[m] = x0 ^ x1 of threefry2x32(key, (hi32(m), lo32(m))=(0, m))
// (legacy mode used pairs (m, m+8192) and one word — rounds 1-4.)
// fold_in / key(42) are unchanged by the flag.
// ---------------------------------------------------------------------------

#define SEQ 1024
#define BATCH 16
#define HDIM 1024
#define NSIM 100
#define NCHAIN (NSIM * BATCH)   // 1600

// ------------------------------- threefry ----------------------------------
__device__ __forceinline__ uint32_t rotl32(uint32_t v, int r) {
    return (v << r) | (v >> (32 - r));
}

__device__ __forceinline__ void threefry(uint32_t k0, uint32_t k1,
                                         uint32_t c0, uint32_t c1,
                                         uint32_t& o0, uint32_t& o1) {
    uint32_t ks0 = k0, ks1 = k1, ks2 = k0 ^ k1 ^ 0x1BD11BDAu;
    uint32_t x0 = c0 + ks0, x1 = c1 + ks1;
#define TFR(r) { x0 += x1; x1 = rotl32(x1, r); x1 ^= x0; }
    TFR(13) TFR(15) TFR(26) TFR(6)   x0 += ks1; x1 += ks2 + 1u;
    TFR(17) TFR(29) TFR(16) TFR(24)  x0 += ks2; x1 += ks0 + 2u;
    TFR(13) TFR(15) TFR(26) TFR(6)   x0 += ks0; x1 += ks1 + 3u;
    TFR(17) TFR(29) TFR(16) TFR(24)  x0 += ks1; x1 += ks2 + 4u;
    TFR(13) TFR(15) TFR(26) TFR(6)   x0 += ks2; x1 += ks0 + 5u;
#undef TFR
    o0 = x0; o1 = x1;
}

__device__ __forceinline__ bool better(float va, int ia, float vb, int ib) {
    return (va > vb) || (va == vb && ia < ib);
}

// ------------------------------- GEMM (fp64 accum) -------------------------
__global__ __launch_bounds__(256)
void gemm_f64acc(const float* __restrict__ A1, long lda1, const int* __restrict__ a1rows,
                 const float* __restrict__ A2, long lda2, const int* __restrict__ a2rows,
                 int K1,
                 const float* __restrict__ W, const float* __restrict__ bias,
                 const float* __restrict__ Cadd,
                 float* __restrict__ C, long ldc,
                 int M, int N, int K, int doGelu) {
    __shared__ float As[16][64];
    __shared__ float Bs[16][64];
    int tid = threadIdx.x;
    int row0 = blockIdx.y * 64, col0 = blockIdx.x * 64;
    int tx = tid & 15, ty = tid >> 4;
    double acc[4][4] = {};
    for (int k0 = 0; k0 < K; k0 += 16) {
#pragma unroll
        for (int l = 0; l < 4; ++l) {
            int e = tid + 256 * l;       // 0..1023
            int m = e >> 4, kk = e & 15;
            int gm = row0 + m, gk = k0 + kk;
            float v = 0.f;
            if (gm < M) {
                if (gk < K1) {
                    long r = a1rows ? (long)a1rows[gm] : (long)gm;
                    v = A1[r * lda1 + gk];
                } else {
                    long r = a2rows ? (long)a2rows[gm] : (long)gm;
                    v = A2[r * lda2 + (gk - K1)];
                }
            }
            As[kk][m] = v;
        }
#pragma unroll
        for (int l = 0; l < 4; ++l) {
            int e = tid + 256 * l;
            int kk = e >> 6, n = e & 63;
            int gn = col0 + n, gk = k0 + kk;
            float v = 0.f;
            if (gn < N) v = W[(long)gk * N + gn];
            Bs[kk][n] = v;
        }
        __syncthreads();
#pragma unroll
        for (int kk = 0; kk < 16; ++kk) {
            double a[4], b[4];
#pragma unroll
            for (int i = 0; i < 4; i++) a[i] = (double)As[kk][ty * 4 + i];
#pragma unroll
            for (int j = 0; j < 4; j++) b[j] = (double)Bs[kk][tx * 4 + j];
#pragma unroll
            for (int i = 0; i < 4; i++)
#pragma unroll
                for (int j = 0; j < 4; j++)
                    acc[i][j] = fma(a[i], b[j], acc[i][j]);
        }
        __syncthreads();
    }
#pragma unroll
    for (int i = 0; i < 4; i++) {
        int gm = row0 + ty * 4 + i;
        if (gm >= M) continue;
#pragma unroll
        for (int j = 0; j < 4; j++) {
            int gn = col0 + tx * 4 + j;
            if (gn >= N) continue;
            double v = acc[i][j] + (double)bias[gn];
            if (doGelu) v = 0.5 * v * (1.0 + erf(v * 0.70710678118654752440));
            if (Cadd) v += (double)Cadd[(long)gm * ldc + gn];
            C[(long)gm * ldc + gn] = (float)v;
        }
    }
}

// --------------------------- small kernels ---------------------------------
__global__ void wp2mean_kernel(const float* __restrict__ Wp2,
                               const float* __restrict__ bp2,
                               float* __restrict__ outv) {
    __shared__ double sb[256];
    int r = blockIdx.x, tid = threadIdx.x;
    const float* src = (r < 1024) ? (Wp2 + (size_t)r * 1024) : bp2;
    double s = 0.0;
    for (int k = tid; k < 1024; k += 256) s += (double)src[k];
    sb[tid] = s; __syncthreads();
    for (int off = 128; off > 0; off >>= 1) {
        if (tid < off) sb[tid] += sb[tid + off];
        __syncthreads();
    }
    if (tid == 0) outv[r] = (float)(sb[0] * (1.0 / 1024.0));
}

__global__ void rootmean_kernel(const float* __restrict__ root, float* __restrict__ rmean) {
    int b = blockIdx.x;
    int h = blockIdx.y * 256 + threadIdx.x;
    const float* base = root + (size_t)b * (SEQ * HDIM) + h;
    double s = 0.0;
    for (int ss = 0; ss < SEQ; ss++) s += (double)base[(size_t)ss * HDIM];
    rmean[b * HDIM + h] = (float)(s * (1.0 / 1024.0));
}

__global__ void sims_kernel(const float* __restrict__ logits, int* __restrict__ sims) {
    int b = threadIdx.x;
    if (b >= BATCH) return;
    float best = logits[b * 5 + 0]; int biv = 0;
    for (int i = 1; i < 5; i++) {
        float v = logits[b * 5 + i];
        if (v > best) { best = v; biv = i; }   // first-max = jnp.argmax
    }
    const int opt[5] = {10, 25, 50, 75, 100};
    sims[b] = opt[biv];
}

// focus logits: fp64 accum, stored FP32 (the dtype the refs sort in)
__global__ void focus_kernel(const float* __restrict__ h, const float* __restrict__ wp2m,
                             const int* __restrict__ amask, float* __restrict__ fl) {
    __shared__ double sb[256];
    int m = blockIdx.x, tid = threadIdx.x;
    const float* hr = h + (size_t)m * HDIM;
    double s = 0.0;
    for (int k = tid; k < HDIM; k += 256) s += (double)hr[k] * (double)wp2m[k];
    sb[tid] = s; __syncthreads();
    for (int off = 128; off > 0; off >>= 1) {
        if (tid < off) sb[tid] += sb[tid + off];
        __syncthreads();
    }
    if (tid == 0) {
        float v = (float)(sb[0] + (double)wp2m[1024]);
        if (amask[m] == 0) v = -1e9f;
        fl[m] = v;
    }
}

// Per (t,b): JAX PARTITIONABLE threefry bits; gumbel with fp32 rounding at
// each step (correctly-rounded f32 logs), fp32 add, fp32 ordering.
__global__ void gumbel_kernel(const float* __restrict__ fl,
                              int* __restrict__ idxj, int* __restrict__ vidx) {
    __shared__ float sv[256][3];
    __shared__ int   si[256][3];
    int blk = blockIdx.x;           // c = t*16+b
    int t = blk >> 4, b = blk & 15;
    uint32_t kk0, kk1;
    threefry(0u, 42u, 0u, (uint32_t)t, kk0, kk1);   // fold_in(key(42), t)
    int tid = threadIdx.x;
    float bv[3] = {-INFINITY, -INFINITY, -INFINITY};
    int   bi[3] = {0x7FFFFFFF, 0x7FFFFFFF, 0x7FFFFFFF};
    for (int s = tid; s < SEQ; s += 256) {
        uint32_t m = (uint32_t)(b * SEQ + s);   // flat 64-bit counter = (0, m)
        uint32_t y0, y1;
        threefry(kk0, kk1, 0u, m, y0, y1);
        uint32_t bits = y0 ^ y1;                // partitionable: xor of both words
        float f = __uint_as_float((bits >> 9) | 0x3F800000u) - 1.0f;
        float u = fmaxf(1.17549435e-38f, f);
        // g = -log32(-log32(u)), each log correctly rounded to fp32
        float l1 = (float)log((double)u);
        float l2 = (float)log(-(double)l1);
        float g  = -l2;
        float val = fl[b * SEQ + s] + g;        // fp32 add, like the refs
        if (better(val, s, bv[2], bi[2])) {
            bv[2] = val; bi[2] = s;
            if (better(bv[2], bi[2], bv[1], bi[1])) {
                float tv = bv[1]; int ti = bi[1];
                bv[1] = bv[2]; bi[1] = bi[2]; bv[2] = tv; bi[2] = ti;
            }
            if (better(bv[1], bi[1], bv[0], bi[0])) {
                float tv = bv[0]; int ti = bi[0];
                bv[0] = bv[1]; bi[0] = bi[1]; bv[1] = tv; bi[1] = ti;
            }
        }
    }
    sv[tid][0] = bv[0]; sv[tid][1] = bv[1]; sv[tid][2] = bv[2];
    si[tid][0] = bi[0]; si[tid][1] = bi[1]; si[tid][2] = bi[2];
    __syncthreads();
    for (int off = 128; off > 0; off >>= 1) {
        if (tid < off) {
            float av[3] = {sv[tid][0], sv[tid][1], sv[tid][2]};
            int   ai[3] = {si[tid][0], si[tid][1], si[tid][2]};
            float cv[3] = {sv[tid + off][0], sv[tid + off][1], sv[tid + off][2]};
            int   ci[3] = {si[tid + off][0], si[tid + off][1], si[tid + off][2]};
            float rv[3]; int ri[3]; int pa = 0, pb = 0;
#pragma unroll
            for (int r = 0; r < 3; r++) {
                if (better(av[pa], ai[pa], cv[pb], ci[pb])) { rv[r] = av[pa]; ri[r] = ai[pa]; pa++; }
                else                                        { rv[r] = cv[pb]; ri[r] = ci[pb]; pb++; }
            }
            sv[tid][0] = rv[0]; sv[tid][1] = rv[1]; sv[tid][2] = rv[2];
            si[tid][0] = ri[0]; si[tid][1] = ri[1]; si[tid][2] = ri[2];
        }
        __syncthreads();
    }
    if (tid == 0) {
        idxj[0 * NCHAIN + blk] = b * SEQ + si[0][0];
        idxj[1 * NCHAIN + blk] = b * SEQ + si[0][1];
        idxj[2 * NCHAIN + blk] = b * SEQ + si[0][2];
        vidx[blk] = b;
    }
}

__global__ void meaninit_kernel(const float* __restrict__ rmean, float* __restrict__ mean_cur) {
    int e = blockIdx.x * 256 + threadIdx.x;     // NCHAIN*HDIM
    int c = e >> 10, hh = e & 1023;
    mean_cur[e] = rmean[(c & 15) * HDIM + hh];
}

__global__ void meanupd_kernel(const float* __restrict__ NSj, const float* __restrict__ root,
                               const int* __restrict__ idx, float* __restrict__ mean_cur) {
    int e = blockIdx.x * 256 + threadIdx.x;
    int c = e >> 10, hh = e & 1023;
    int r = idx[c];
    double m = (double)mean_cur[e] +
               ((double)NSj[e] - (double)root[(size_t)r * HDIM + hh]) * (1.0 / 1024.0);
    mean_cur[e] = (float)m;
}

__global__ void valdot_kernel(const float* __restrict__ HV, const float* __restrict__ Wav2,
                              const float* __restrict__ bav2, float* __restrict__ w) {
    __shared__ double sb[256];
    int c = blockIdx.x, tid = threadIdx.x;
    double s = 0.0;
    for (int k = tid; k < HDIM; k += 256) s += (double)HV[(size_t)c * HDIM + k] * (double)Wav2[k];
    sb[tid] = s; __syncthreads();
    for (int off = 128; off > 0; off >>= 1) {
        if (tid < off) sb[tid] += sb[tid + off];
        __syncthreads();
    }
    if (tid == 0) {
        double v = sb[0] + (double)bav2[0];
        w[c] = (float)(1.0 / (1.0 + exp(-v)));
    }
}

__global__ void wsum_kernel(const float* __restrict__ w, const int* __restrict__ sims,
                            double* __restrict__ Wsum) {
    int b = threadIdx.x;
    if (b >= BATCH) return;
    int sb = sims[b];
    double s = 0.0;
    for (int t = 0; t < sb; t++) s += (double)w[t * BATCH + b];   // scan order
    Wsum[b] = s;
}

__global__ void accinit_kernel(const float* __restrict__ root, const double* __restrict__ Wsum,
                               float* __restrict__ acc) {
    size_t e = (size_t)blockIdx.x * 256 + threadIdx.x;
    int b = (int)(e >> 20);                               // SEQ*HDIM = 2^20 per batch
    acc[e] = (float)((1.0 + Wsum[b]) * (double)root[e]);
}

__global__ __launch_bounds__(1024)
void corrections_kernel(const float* __restrict__ NSbase, const float* __restrict__ root,
                        const float* __restrict__ w, const int* __restrict__ sims,
                        const int* __restrict__ idxj, float* __restrict__ acc) {
    int b = blockIdx.x;
    int hh = threadIdx.x;   // 1024 threads
    int sb = sims[b];
    for (int t = 0; t < sb; ++t) {          // t ascending = scan order
        int c = t * BATCH + b;
        double wv = (double)w[c];
#pragma unroll
        for (int j = 0; j < 3; j++) {
            int idx = idxj[j * NCHAIN + c];
            double ns = (double)NSbase[((size_t)(j * NCHAIN + c)) * HDIM + hh];
            size_t o = (size_t)idx * HDIM + hh;
            acc[o] = (float)((double)acc[o] + wv * (ns - (double)root[o]));
        }
    }
}

// ------------------------------- launch ------------------------------------
static inline void gemm(hipStream_t st,
                        const float* A1, long lda1, const int* a1r,
                        const float* A2, long lda2, const int* a2r, int K1,
                        const float* W, const float* bias, const float* Cadd,
                        float* C, long ldc, int M, int N, int K, int act) {
    dim3 g((N + 63) / 64, (M + 63) / 64);
    gemm_f64acc<<<g, 256, 0, st>>>(A1, lda1, a1r, A2, lda2, a2r, K1, W, bias, Cadd,
                                   C, ldc, M, N, K, act);
}

extern "C" void kernel_launch(void* const* d_in, const int* in_sizes, int n_in,
                              void* d_out, int out_size, void* d_ws, size_t ws_size,
                              hipStream_t stream) {
    (void)in_sizes; (void)n_in; (void)out_size; (void)ws_size;
    const float* root = (const float*)d_in[0];
    const int*   amask = (const int*)d_in[1];
    const float* Wsc1 = (const float*)d_in[2];  const float* bsc1 = (const float*)d_in[3];
    const float* Wsc2 = (const float*)d_in[4];  const float* bsc2 = (const float*)d_in[5];
    const float* Wp1  = (const float*)d_in[6];  const float* bp1  = (const float*)d_in[7];
    const float* Wp2  = (const float*)d_in[8];  const float* bp2  = (const float*)d_in[9];
    const float* Wt1  = (const float*)d_in[10]; const float* bt1  = (const float*)d_in[11];
    const float* Wt2  = (const float*)d_in[12]; const float* bt2  = (const float*)d_in[13];
    const float* Wav1 = (const float*)d_in[14]; const float* bav1 = (const float*)d_in[15];
    const float* Wav2 = (const float*)d_in[16]; const float* bav2 = (const float*)d_in[17];
    const float* Wg1  = (const float*)d_in[18]; const float* bg1  = (const float*)d_in[19];
    const float* Wg2  = (const float*)d_in[20]; const float* bg2  = (const float*)d_in[21];
    float* out = (float*)d_out;

    // ---- workspace carving ----
    char* p = (char*)d_ws;
    auto carve = [&](size_t nbytes) -> void* {
        void* r = (void*)p; p += (nbytes + 255) & ~(size_t)255; return r;
    };
    float*  h_buf    = (float*)carve((size_t)BATCH * SEQ * HDIM * 4);  // 64 MiB
    float*  mean_cur = (float*)carve((size_t)NCHAIN * HDIM * 4);
    float*  rmean    = (float*)carve(BATCH * HDIM * 4);
    float*  T1       = (float*)carve(BATCH * HDIM * 4);
    float*  logits   = (float*)carve(128 * 4);
    float*  wp2m     = (float*)carve(1040 * 4);
    float*  fl       = (float*)carve(BATCH * SEQ * 4);
    float*  wbuf     = (float*)carve(NCHAIN * 4);
    double* Wsum     = (double*)carve(64 * 8);
    int*    sims     = (int*)carve(64 * 4);
    int*    idxj     = (int*)carve(3 * NCHAIN * 4);
    int*    vidx     = (int*)carve(NCHAIN * 4);
    // NS[3] lives inside h_buf past the H1 region (policy-h is dead by then)
    float* NS = h_buf + (size_t)2 * 1024 * 1024;   // 3*1600*1024 floats used
    float* H1 = h_buf;                              // [1600,1024] scratch

    const long SH = (long)SEQ * HDIM;

    // 1) policy Wp2 row means (+ bias mean)
    wp2mean_kernel<<<1025, 256, 0, stream>>>(Wp2, bp2, wp2m);
    // 2) root mean over S
    rootmean_kernel<<<dim3(BATCH, HDIM / 256), 256, 0, stream>>>(root, rmean);
    // 3) controller MLP -> sims
    gemm(stream, root, SH, nullptr, nullptr, 0, nullptr, 1024,
         Wsc1, bsc1, nullptr, T1, 1024, BATCH, 1024, 1024, 1);
    gemm(stream, T1, 1024, nullptr, nullptr, 0, nullptr, 1024,
         Wsc2, bsc2, nullptr, logits, 5, BATCH, 5, 1024, 0);
    sims_kernel<<<1, 64, 0, stream>>>(logits, sims);
    // 4) policy layer-1 -> h_buf
    gemm(stream, root, 1024, nullptr, nullptr, 0, nullptr, 1024,
         Wp1, bp1, nullptr, h_buf, 1024, BATCH * SEQ, 1024, 1024, 1);
    // 5) focus logits (fp32 storage)
    focus_kernel<<<BATCH * SEQ, 256, 0, stream>>>(h_buf, wp2m, amask, fl);
    // 6) gumbel top-3 per (t,b): PARTITIONABLE threefry, fp32 ordering
    gumbel_kernel<<<NCHAIN, 256, 0, stream>>>(fl, idxj, vidx);
    // 7) per-chain running mean init
    meaninit_kernel<<<NCHAIN * HDIM / 256, 256, 0, stream>>>(rmean, mean_cur);
    // 8) three sequential transitions, batched over all 1600 chains
    for (int j = 0; j < 3; j++) {
        gemm(stream, mean_cur, 1024, nullptr, root, 1024, idxj + j * NCHAIN, 1024,
             Wt1, bt1, nullptr, H1, 1024, NCHAIN, 1024, 2048, 1);
        gemm(stream, H1, 1024, nullptr, nullptr, 0, nullptr, 1024,
             Wt2, bt2, nullptr, NS + (size_t)j * NCHAIN * HDIM, 1024,
             NCHAIN, 1024, 1024, 0);
        meanupd_kernel<<<NCHAIN * HDIM / 256, 256, 0, stream>>>(
            NS + (size_t)j * NCHAIN * HDIM, root, idxj + j * NCHAIN, mean_cur);
    }
    // 9) action value -> w
    gemm(stream, rmean, 1024, vidx, mean_cur, 1024, nullptr, 1024,
         Wav1, bav1, nullptr, H1, 1024, NCHAIN, 1024, 2048, 1);
    valdot_kernel<<<NCHAIN, 256, 0, stream>>>(H1, Wav2, bav2, wbuf);
    wsum_kernel<<<1, 64, 0, stream>>>(wbuf, sims, Wsum);
    // 10) acc = (1+Wsum)*root, then sparse corrections (acc lives in d_out)
    accinit_kernel<<<(BATCH * SEQ * HDIM) / 256, 256, 0, stream>>>(root, Wsum, out);
    corrections_kernel<<<BATCH, 1024, 0, stream>>>(NS, root, wbuf, sims, idxj, out);
    // 11) aggregation: h = gelu([root, acc] @ Wg1 + bg1); out = hidden + h @ Wg2 + bg2
    gemm(stream, root, 1024, nullptr, out, 1024, nullptr, 1024,
         Wg1, bg1, nullptr, h_buf, 1024, BATCH * SEQ, 1024, 2048, 1);
    gemm(stream, h_buf, 1024, nullptr, nullptr, 0, nullptr, 1024,
         Wg2, bg2, root, out, 1024, BATCH * SEQ, 1024, 1024, 0);
}

// Round 6
// 3053.083 us; speedup vs baseline: 2.3659x; 2.3659x over previous
//
#include <hip/hip_runtime.h>
#include <hip/hip_bf16.h>
#include <cstdint>
#include <math.h>

// ---------------------------------------------------------------------------
// AdaptiveMCTSReasoner  B=16, S=1024, H=1024, MAX_SIMS=100, K_FOCUS=3
// Round 6: precision-split for speed.
//  - gumbel/selection path: UNCHANGED from round 5 (partitionable threefry).
//  - controller MLP: fp64 (tiny, protects argmax).
//  - policy layer-1: fp32 GEMM (fl error ~1e-7 via tiny wp2m dot, safe).
//  - transitions/action-value/aggregation: bf16 MFMA GEMM (continuous only).
// ---------------------------------------------------------------------------

#define SEQ 1024
#define BATCH 16
#define HDIM 1024
#define NSIM 100
#define NCHAIN (NSIM * BATCH)   // 1600

typedef short bf16x8 __attribute__((ext_vector_type(8)));
typedef short short4v __attribute__((ext_vector_type(4)));
typedef float f32x4 __attribute__((ext_vector_type(4)));
typedef float float4v __attribute__((ext_vector_type(4)));

__device__ __forceinline__ unsigned short f2bf(float f) {
    union { float f; uint32_t u; } c; c.f = f;
    uint32_t u = c.u;
    return (unsigned short)((u + 0x7FFFu + ((u >> 16) & 1u)) >> 16);   // RNE
}

// ------------------------------- threefry ----------------------------------
__device__ __forceinline__ uint32_t rotl32(uint32_t v, int r) {
    return (v << r) | (v >> (32 - r));
}

__device__ __forceinline__ void threefry(uint32_t k0, uint32_t k1,
                                         uint32_t c0, uint32_t c1,
                                         uint32_t& o0, uint32_t& o1) {
    uint32_t ks0 = k0, ks1 = k1, ks2 = k0 ^ k1 ^ 0x1BD11BDAu;
    uint32_t x0 = c0 + ks0, x1 = c1 + ks1;
#define TFR(r) { x0 += x1; x1 = rotl32(x1, r); x1 ^= x0; }
    TFR(13) TFR(15) TFR(26) TFR(6)   x0 += ks1; x1 += ks2 + 1u;
    TFR(17) TFR(29) TFR(16) TFR(24)  x0 += ks2; x1 += ks0 + 2u;
    TFR(13) TFR(15) TFR(26) TFR(6)   x0 += ks0; x1 += ks1 + 3u;
    TFR(17) TFR(29) TFR(16) TFR(24)  x0 += ks1; x1 += ks2 + 4u;
    TFR(13) TFR(15) TFR(26) TFR(6)   x0 += ks2; x1 += ks0 + 5u;
#undef TFR
    o0 = x0; o1 = x1;
}

__device__ __forceinline__ bool better(float va, int ia, float vb, int ib) {
    return (va > vb) || (va == vb && ia < ib);
}

// ------------------------------- GEMM (fp64 accum, controller only) --------
__global__ __launch_bounds__(256)
void gemm_f64acc(const float* __restrict__ A1, long lda1, const int* __restrict__ a1rows,
                 const float* __restrict__ A2, long lda2, const int* __restrict__ a2rows,
                 int K1,
                 const float* __restrict__ W, const float* __restrict__ bias,
                 const float* __restrict__ Cadd,
                 float* __restrict__ C, long ldc,
                 int M, int N, int K, int doGelu) {
    __shared__ float As[16][64];
    __shared__ float Bs[16][64];
    int tid = threadIdx.x;
    int row0 = blockIdx.y * 64, col0 = blockIdx.x * 64;
    int tx = tid & 15, ty = tid >> 4;
    double acc[4][4] = {};
    for (int k0 = 0; k0 < K; k0 += 16) {
#pragma unroll
        for (int l = 0; l < 4; ++l) {
            int e = tid + 256 * l;
            int m = e >> 4, kk = e & 15;
            int gm = row0 + m, gk = k0 + kk;
            float v = 0.f;
            if (gm < M) {
                if (gk < K1) {
                    long r = a1rows ? (long)a1rows[gm] : (long)gm;
                    v = A1[r * lda1 + gk];
                } else {
                    long r = a2rows ? (long)a2rows[gm] : (long)gm;
                    v = A2[r * lda2 + (gk - K1)];
                }
            }
            As[kk][m] = v;
        }
#pragma unroll
        for (int l = 0; l < 4; ++l) {
            int e = tid + 256 * l;
            int kk = e >> 6, n = e & 63;
            int gn = col0 + n, gk = k0 + kk;
            float v = 0.f;
            if (gn < N) v = W[(long)gk * N + gn];
            Bs[kk][n] = v;
        }
        __syncthreads();
#pragma unroll
        for (int kk = 0; kk < 16; ++kk) {
            double a[4], b[4];
#pragma unroll
            for (int i = 0; i < 4; i++) a[i] = (double)As[kk][ty * 4 + i];
#pragma unroll
            for (int j = 0; j < 4; j++) b[j] = (double)Bs[kk][tx * 4 + j];
#pragma unroll
            for (int i = 0; i < 4; i++)
#pragma unroll
                for (int j = 0; j < 4; j++)
                    acc[i][j] = fma(a[i], b[j], acc[i][j]);
        }
        __syncthreads();
    }
#pragma unroll
    for (int i = 0; i < 4; i++) {
        int gm = row0 + ty * 4 + i;
        if (gm >= M) continue;
#pragma unroll
        for (int j = 0; j < 4; j++) {
            int gn = col0 + tx * 4 + j;
            if (gn >= N) continue;
            double v = acc[i][j] + (double)bias[gn];
            if (doGelu) v = 0.5 * v * (1.0 + erf(v * 0.70710678118654752440));
            if (Cadd) v += (double)Cadd[(long)gm * ldc + gn];
            C[(long)gm * ldc + gn] = (float)v;
        }
    }
}

// ------------------------------- GEMM (fp32, policy) -----------------------
__global__ __launch_bounds__(256)
void gemm_f32(const float* __restrict__ A, long lda,
              const float* __restrict__ W, const float* __restrict__ bias,
              float* __restrict__ C, long ldc,
              int M, int N, int K, int doGelu) {
    __shared__ float As[16][64];
    __shared__ float Bs[16][64];
    int tid = threadIdx.x;
    int row0 = blockIdx.y * 64, col0 = blockIdx.x * 64;
    int tx = tid & 15, ty = tid >> 4;
    float acc[4][4] = {};
    for (int k0 = 0; k0 < K; k0 += 16) {
#pragma unroll
        for (int l = 0; l < 4; ++l) {
            int e = tid + 256 * l;
            int m = e >> 4, kk = e & 15;
            int gm = row0 + m, gk = k0 + kk;
            As[kk][m] = (gm < M) ? A[(long)gm * lda + gk] : 0.f;
        }
#pragma unroll
        for (int l = 0; l < 4; ++l) {
            int e = tid + 256 * l;
            int kk = e >> 6, n = e & 63;
            Bs[kk][n] = W[(long)(k0 + kk) * N + col0 + n];
        }
        __syncthreads();
#pragma unroll
        for (int kk = 0; kk < 16; ++kk) {
            float a[4], b[4];
#pragma unroll
            for (int i = 0; i < 4; i++) a[i] = As[kk][ty * 4 + i];
#pragma unroll
            for (int j = 0; j < 4; j++) b[j] = Bs[kk][tx * 4 + j];
#pragma unroll
            for (int i = 0; i < 4; i++)
#pragma unroll
                for (int j = 0; j < 4; j++)
                    acc[i][j] = fmaf(a[i], b[j], acc[i][j]);
        }
        __syncthreads();
    }
#pragma unroll
    for (int i = 0; i < 4; i++) {
        int gm = row0 + ty * 4 + i;
        if (gm >= M) continue;
#pragma unroll
        for (int j = 0; j < 4; j++) {
            int gn = col0 + tx * 4 + j;
            float v = acc[i][j] + bias[gn];
            if (doGelu) v = 0.5f * v * (1.0f + erff(v * 0.70710678f));
            C[(long)gm * ldc + gn] = v;
        }
    }
}

// ------------------------- GEMM (bf16 MFMA, bulk) ---------------------------
// C[M,N] = act(A @ W + bias)(+Cadd); A col k from A1 (k<K1) else A2; optional
// per-row gathers. A/B converted fp32->bf16 at staging. 128x128 tile, BK=32,
// 4 waves (2x2 of 64x64), mfma_f32_16x16x32_bf16.
#define APAD 40   // padded k-stride (bf16 elems): 80B, 16B-aligned
__global__ __launch_bounds__(256)
void gemm_bf16(const float* __restrict__ A1, long lda1, const int* __restrict__ a1rows,
               const float* __restrict__ A2, long lda2, const int* __restrict__ a2rows,
               int K1,
               const float* __restrict__ W, const float* __restrict__ bias,
               const float* __restrict__ Cadd,
               float* __restrict__ C, long ldc,
               int M, int N, int K, int doGelu) {
    __shared__ unsigned short As[128][APAD];   // [m][k]
    __shared__ unsigned short Bs[128][APAD];   // [n][k] (transposed)
    __shared__ int r1[128], r2[128];
    int tid = threadIdx.x;
    int row0 = blockIdx.y * 128, col0 = blockIdx.x * 128;
    if (tid < 128) {
        int gm = row0 + tid;
        int gmc = (gm < M) ? gm : 0;
        r1[tid] = a1rows ? a1rows[gmc] : gmc;
        r2[tid] = a2rows ? a2rows[gmc] : gmc;
    }
    int wid = tid >> 6, lane = tid & 63;
    int wr = wid >> 1, wc = wid & 1;
    int lhi = lane >> 4, llo = lane & 15;
    f32x4 acc[4][4];
#pragma unroll
    for (int i = 0; i < 4; i++)
#pragma unroll
        for (int j = 0; j < 4; j++) acc[i][j] = (f32x4){0.f, 0.f, 0.f, 0.f};
    __syncthreads();

    for (int k0 = 0; k0 < K; k0 += 32) {
        const bool fromA1 = (k0 < K1);
        const float* Asrc = fromA1 ? A1 : A2;
        const long lda = fromA1 ? lda1 : lda2;
        const int* rsel = fromA1 ? r1 : r2;
        const int kb = fromA1 ? k0 : (k0 - K1);
        // stage A: 128 rows x 32 k (float4 reads, 4xbf16 writes)
#pragma unroll
        for (int l = 0; l < 4; ++l) {
            int pos = tid + 256 * l;            // 0..1023
            int m = pos >> 3, kq = (pos & 7) << 2;
            float4v v = {0.f, 0.f, 0.f, 0.f};
            if (row0 + m < M)
                v = *(const float4v*)&Asrc[(long)rsel[m] * lda + kb + kq];
            short4v s;
            s[0] = (short)f2bf(v[0]); s[1] = (short)f2bf(v[1]);
            s[2] = (short)f2bf(v[2]); s[3] = (short)f2bf(v[3]);
            *(short4v*)&As[m][kq] = s;
        }
        // stage B: 32 k x 128 n, transposed into Bs[n][k]
#pragma unroll
        for (int l = 0; l < 4; ++l) {
            int pos = tid + 256 * l;
            int gk = pos >> 5, gnq = (pos & 31) << 2;
            float4v v = *(const float4v*)&W[(long)(k0 + gk) * N + col0 + gnq];
            Bs[gnq + 0][gk] = f2bf(v[0]);
            Bs[gnq + 1][gk] = f2bf(v[1]);
            Bs[gnq + 2][gk] = f2bf(v[2]);
            Bs[gnq + 3][gk] = f2bf(v[3]);
        }
        __syncthreads();
        bf16x8 af[4], bfr[4];
#pragma unroll
        for (int mt = 0; mt < 4; ++mt)
            af[mt] = *(bf16x8*)&As[wr * 64 + mt * 16 + llo][lhi * 8];
#pragma unroll
        for (int nt = 0; nt < 4; ++nt)
            bfr[nt] = *(bf16x8*)&Bs[wc * 64 + nt * 16 + llo][lhi * 8];
#pragma unroll
        for (int mt = 0; mt < 4; ++mt)
#pragma unroll
            for (int nt = 0; nt < 4; ++nt)
                acc[mt][nt] = __builtin_amdgcn_mfma_f32_16x16x32_bf16(
                    af[mt], bfr[nt], acc[mt][nt], 0, 0, 0);
        __syncthreads();
    }
    // epilogue: C/D layout col=lane&15, row=(lane>>4)*4+reg  [m89-verified]
#pragma unroll
    for (int mt = 0; mt < 4; ++mt) {
#pragma unroll
        for (int nt = 0; nt < 4; ++nt) {
            int gn = col0 + wc * 64 + nt * 16 + llo;
#pragma unroll
            for (int r = 0; r < 4; ++r) {
                int gm = row0 + wr * 64 + mt * 16 + lhi * 4 + r;
                if (gm >= M) continue;
                float v = acc[mt][nt][r] + bias[gn];
                if (doGelu) v = 0.5f * v * (1.0f + erff(v * 0.70710678f));
                if (Cadd) v += Cadd[(long)gm * ldc + gn];
                C[(long)gm * ldc + gn] = v;
            }
        }
    }
}

// --------------------------- small kernels ---------------------------------
__global__ void wp2mean_kernel(const float* __restrict__ Wp2,
                               const float* __restrict__ bp2,
                               float* __restrict__ outv) {
    __shared__ double sb[256];
    int r = blockIdx.x, tid = threadIdx.x;
    const float* src = (r < 1024) ? (Wp2 + (size_t)r * 1024) : bp2;
    double s = 0.0;
    for (int k = tid; k < 1024; k += 256) s += (double)src[k];
    sb[tid] = s; __syncthreads();
    for (int off = 128; off > 0; off >>= 1) {
        if (tid < off) sb[tid] += sb[tid + off];
        __syncthreads();
    }
    if (tid == 0) outv[r] = (float)(sb[0] * (1.0 / 1024.0));
}

__global__ void rootmean_kernel(const float* __restrict__ root, float* __restrict__ rmean) {
    int b = blockIdx.x;
    int h = blockIdx.y * 256 + threadIdx.x;
    const float* base = root + (size_t)b * (SEQ * HDIM) + h;
    double s = 0.0;
    for (int ss = 0; ss < SEQ; ss++) s += (double)base[(size_t)ss * HDIM];
    rmean[b * HDIM + h] = (float)(s * (1.0 / 1024.0));
}

__global__ void sims_kernel(const float* __restrict__ logits, int* __restrict__ sims) {
    int b = threadIdx.x;
    if (b >= BATCH) return;
    float best = logits[b * 5 + 0]; int biv = 0;
    for (int i = 1; i < 5; i++) {
        float v = logits[b * 5 + i];
        if (v > best) { best = v; biv = i; }   // first-max = jnp.argmax
    }
    const int opt[5] = {10, 25, 50, 75, 100};
    sims[b] = opt[biv];
}

// focus logits: fp64 dot, stored FP32 (the dtype the refs sort in)
__global__ void focus_kernel(const float* __restrict__ h, const float* __restrict__ wp2m,
                             const int* __restrict__ amask, float* __restrict__ fl) {
    __shared__ double sb[256];
    int m = blockIdx.x, tid = threadIdx.x;
    const float* hr = h + (size_t)m * HDIM;
    double s = 0.0;
    for (int k = tid; k < HDIM; k += 256) s += (double)hr[k] * (double)wp2m[k];
    sb[tid] = s; __syncthreads();
    for (int off = 128; off > 0; off >>= 1) {
        if (tid < off) sb[tid] += sb[tid + off];
        __syncthreads();
    }
    if (tid == 0) {
        float v = (float)(sb[0] + (double)wp2m[1024]);
        if (amask[m] == 0) v = -1e9f;
        fl[m] = v;
    }
}

// Per (t,b): JAX PARTITIONABLE threefry bits (UNCHANGED from round 5 — passing)
__global__ void gumbel_kernel(const float* __restrict__ fl,
                              int* __restrict__ idxj, int* __restrict__ vidx) {
    __shared__ float sv[256][3];
    __shared__ int   si[256][3];
    int blk = blockIdx.x;           // c = t*16+b
    int t = blk >> 4, b = blk & 15;
    uint32_t kk0, kk1;
    threefry(0u, 42u, 0u, (uint32_t)t, kk0, kk1);   // fold_in(key(42), t)
    int tid = threadIdx.x;
    float bv[3] = {-INFINITY, -INFINITY, -INFINITY};
    int   bi[3] = {0x7FFFFFFF, 0x7FFFFFFF, 0x7FFFFFFF};
    for (int s = tid; s < SEQ; s += 256) {
        uint32_t m = (uint32_t)(b * SEQ + s);   // flat 64-bit counter = (0, m)
        uint32_t y0, y1;
        threefry(kk0, kk1, 0u, m, y0, y1);
        uint32_t bits = y0 ^ y1;                // partitionable: xor of both words
        float f = __uint_as_float((bits >> 9) | 0x3F800000u) - 1.0f;
        float u = fmaxf(1.17549435e-38f, f);
        float l1 = (float)log((double)u);
        float l2 = (float)log(-(double)l1);
        float g  = -l2;
        float val = fl[b * SEQ + s] + g;
        if (better(val, s, bv[2], bi[2])) {
            bv[2] = val; bi[2] = s;
            if (better(bv[2], bi[2], bv[1], bi[1])) {
                float tv = bv[1]; int ti = bi[1];
                bv[1] = bv[2]; bi[1] = bi[2]; bv[2] = tv; bi[2] = ti;
            }
            if (better(bv[1], bi[1], bv[0], bi[0])) {
                float tv = bv[0]; int ti = bi[0];
                bv[0] = bv[1]; bi[0] = bi[1]; bv[1] = tv; bi[1] = ti;
            }
        }
    }
    sv[tid][0] = bv[0]; sv[tid][1] = bv[1]; sv[tid][2] = bv[2];
    si[tid][0] = bi[0]; si[tid][1] = bi[1]; si[tid][2] = bi[2];
    __syncthreads();
    for (int off = 128; off > 0; off >>= 1) {
        if (tid < off) {
            float av[3] = {sv[tid][0], sv[tid][1], sv[tid][2]};
            int   ai[3] = {si[tid][0], si[tid][1], si[tid][2]};
            float cv[3] = {sv[tid + off][0], sv[tid + off][1], sv[tid + off][2]};
            int   ci[3] = {si[tid + off][0], si[tid + off][1], si[tid + off][2]};
            float rv[3]; int ri[3]; int pa = 0, pb = 0;
#pragma unroll
            for (int r = 0; r < 3; r++) {
                if (better(av[pa], ai[pa], cv[pb], ci[pb])) { rv[r] = av[pa]; ri[r] = ai[pa]; pa++; }
                else                                        { rv[r] = cv[pb]; ri[r] = ci[pb]; pb++; }
            }
            sv[tid][0] = rv[0]; sv[tid][1] = rv[1]; sv[tid][2] = rv[2];
            si[tid][0] = ri[0]; si[tid][1] = ri[1]; si[tid][2] = ri[2];
        }
        __syncthreads();
    }
    if (tid == 0) {
        idxj[0 * NCHAIN + blk] = b * SEQ + si[0][0];
        idxj[1 * NCHAIN + blk] = b * SEQ + si[0][1];
        idxj[2 * NCHAIN + blk] = b * SEQ + si[0][2];
        vidx[blk] = b;
    }
}

__global__ void meaninit_kernel(const float* __restrict__ rmean, float* __restrict__ mean_cur) {
    int e = blockIdx.x * 256 + threadIdx.x;     // NCHAIN*HDIM
    int c = e >> 10, hh = e & 1023;
    mean_cur[e] = rmean[(c & 15) * HDIM + hh];
}

__global__ void meanupd_kernel(const float* __restrict__ NSj, const float* __restrict__ root,
                               const int* __restrict__ idx, float* __restrict__ mean_cur) {
    int e = blockIdx.x * 256 + threadIdx.x;
    int c = e >> 10, hh = e & 1023;
    int r = idx[c];
    double m = (double)mean_cur[e] +
               ((double)NSj[e] - (double)root[(size_t)r * HDIM + hh]) * (1.0 / 1024.0);
    mean_cur[e] = (float)m;
}

__global__ void valdot_kernel(const float* __restrict__ HV, const float* __restrict__ Wav2,
                              const float* __restrict__ bav2, float* __restrict__ w) {
    __shared__ double sb[256];
    int c = blockIdx.x, tid = threadIdx.x;
    double s = 0.0;
    for (int k = tid; k < HDIM; k += 256) s += (double)HV[(size_t)c * HDIM + k] * (double)Wav2[k];
    sb[tid] = s; __syncthreads();
    for (int off = 128; off > 0; off >>= 1) {
        if (tid < off) sb[tid] += sb[tid + off];
        __syncthreads();
    }
    if (tid == 0) {
        double v = sb[0] + (double)bav2[0];
        w[c] = (float)(1.0 / (1.0 + exp(-v)));
    }
}

__global__ void wsum_kernel(const float* __restrict__ w, const int* __restrict__ sims,
                            double* __restrict__ Wsum) {
    int b = threadIdx.x;
    if (b >= BATCH) return;
    int sb = sims[b];
    double s = 0.0;
    for (int t = 0; t < sb; t++) s += (double)w[t * BATCH + b];   // scan order
    Wsum[b] = s;
}

__global__ void accinit_kernel(const float* __restrict__ root, const double* __restrict__ Wsum,
                               float* __restrict__ acc) {
    size_t e = (size_t)blockIdx.x * 256 + threadIdx.x;
    int b = (int)(e >> 20);                               // SEQ*HDIM = 2^20 per batch
    acc[e] = (float)((1.0 + Wsum[b]) * (double)root[e]);
}

__global__ __launch_bounds__(1024)
void corrections_kernel(const float* __restrict__ NSbase, const float* __restrict__ root,
                        const float* __restrict__ w, const int* __restrict__ sims,
                        const int* __restrict__ idxj, float* __restrict__ acc) {
    int b = blockIdx.x;
    int hh = threadIdx.x;   // 1024 threads
    int sb = sims[b];
    for (int t = 0; t < sb; ++t) {          // t ascending = scan order
        int c = t * BATCH + b;
        double wv = (double)w[c];
#pragma unroll
        for (int j = 0; j < 3; j++) {
            int idx = idxj[j * NCHAIN + c];
            double ns = (double)NSbase[((size_t)(j * NCHAIN + c)) * HDIM + hh];
            size_t o = (size_t)idx * HDIM + hh;
            acc[o] = (float)((double)acc[o] + wv * (ns - (double)root[o]));
        }
    }
}

// ------------------------------- launch ------------------------------------
static inline void gemm64(hipStream_t st,
                          const float* A1, long lda1, const int* a1r,
                          const float* A2, long lda2, const int* a2r, int K1,
                          const float* W, const float* bias, const float* Cadd,
                          float* C, long ldc, int M, int N, int K, int act) {
    dim3 g((N + 63) / 64, (M + 63) / 64);
    gemm_f64acc<<<g, 256, 0, st>>>(A1, lda1, a1r, A2, lda2, a2r, K1, W, bias, Cadd,
                                   C, ldc, M, N, K, act);
}

static inline void gemmbf(hipStream_t st,
                          const float* A1, long lda1, const int* a1r,
                          const float* A2, long lda2, const int* a2r, int K1,
                          const float* W, const float* bias, const float* Cadd,
                          float* C, long ldc, int M, int N, int K, int act) {
    dim3 g(N / 128, (M + 127) / 128);
    gemm_bf16<<<g, 256, 0, st>>>(A1, lda1, a1r, A2, lda2, a2r, K1, W, bias, Cadd,
                                 C, ldc, M, N, K, act);
}

extern "C" void kernel_launch(void* const* d_in, const int* in_sizes, int n_in,
                              void* d_out, int out_size, void* d_ws, size_t ws_size,
                              hipStream_t stream) {
    (void)in_sizes; (void)n_in; (void)out_size; (void)ws_size;
    const float* root = (const float*)d_in[0];
    const int*   amask = (const int*)d_in[1];
    const float* Wsc1 = (const float*)d_in[2];  const float* bsc1 = (const float*)d_in[3];
    const float* Wsc2 = (const float*)d_in[4];  const float* bsc2 = (const float*)d_in[5];
    const float* Wp1  = (const float*)d_in[6];  const float* bp1  = (const float*)d_in[7];
    const float* Wp2  = (const float*)d_in[8];  const float* bp2  = (const float*)d_in[9];
    const float* Wt1  = (const float*)d_in[10]; const float* bt1  = (const float*)d_in[11];
    const float* Wt2  = (const float*)d_in[12]; const float* bt2  = (const float*)d_in[13];
    const float* Wav1 = (const float*)d_in[14]; const float* bav1 = (const float*)d_in[15];
    const float* Wav2 = (const float*)d_in[16]; const float* bav2 = (const float*)d_in[17];
    const float* Wg1  = (const float*)d_in[18]; const float* bg1  = (const float*)d_in[19];
    const float* Wg2  = (const float*)d_in[20]; const float* bg2  = (const float*)d_in[21];
    float* out = (float*)d_out;

    // ---- workspace carving ----
    char* p = (char*)d_ws;
    auto carve = [&](size_t nbytes) -> void* {
        void* r = (void*)p; p += (nbytes + 255) & ~(size_t)255; return r;
    };
    float*  h_buf    = (float*)carve((size_t)BATCH * SEQ * HDIM * 4);  // 64 MiB
    float*  mean_cur = (float*)carve((size_t)NCHAIN * HDIM * 4);
    float*  rmean    = (float*)carve(BATCH * HDIM * 4);
    float*  T1       = (float*)carve(BATCH * HDIM * 4);
    float*  logits   = (float*)carve(128 * 4);
    float*  wp2m     = (float*)carve(1040 * 4);
    float*  fl       = (float*)carve(BATCH * SEQ * 4);
    float*  wbuf     = (float*)carve(NCHAIN * 4);
    double* Wsum     = (double*)carve(64 * 8);
    int*    sims     = (int*)carve(64 * 4);
    int*    idxj     = (int*)carve(3 * NCHAIN * 4);
    int*    vidx     = (int*)carve(NCHAIN * 4);
    // NS[3] lives inside h_buf past the H1 region (policy-h is dead by then)
    float* NS = h_buf + (size_t)2 * 1024 * 1024;   // 3*1600*1024 floats used
    float* H1 = h_buf;                              // [1600,1024] scratch

    const long SH = (long)SEQ * HDIM;

    // 1) policy Wp2 row means (+ bias mean)
    wp2mean_kernel<<<1025, 256, 0, stream>>>(Wp2, bp2, wp2m);
    // 2) root mean over S
    rootmean_kernel<<<dim3(BATCH, HDIM / 256), 256, 0, stream>>>(root, rmean);
    // 3) controller MLP -> sims (fp64, protects argmax)
    gemm64(stream, root, SH, nullptr, nullptr, 0, nullptr, 1024,
           Wsc1, bsc1, nullptr, T1, 1024, BATCH, 1024, 1024, 1);
    gemm64(stream, T1, 1024, nullptr, nullptr, 0, nullptr, 1024,
           Wsc2, bsc2, nullptr, logits, 5, BATCH, 5, 1024, 0);
    sims_kernel<<<1, 64, 0, stream>>>(logits, sims);
    // 4) policy layer-1 -> h_buf (fp32: fl error stays ~1e-7 via tiny wp2m dot)
    {
        dim3 g(1024 / 64, (BATCH * SEQ) / 64);
        gemm_f32<<<g, 256, 0, stream>>>(root, 1024, Wp1, bp1, h_buf, 1024,
                                        BATCH * SEQ, 1024, 1024, 1);
    }
    // 5) focus logits (fp64 dot)
    focus_kernel<<<BATCH * SEQ, 256, 0, stream>>>(h_buf, wp2m, amask, fl);
    // 6) gumbel top-3 per (t,b): PARTITIONABLE threefry (unchanged)
    gumbel_kernel<<<NCHAIN, 256, 0, stream>>>(fl, idxj, vidx);
    // 7) per-chain running mean init
    meaninit_kernel<<<NCHAIN * HDIM / 256, 256, 0, stream>>>(rmean, mean_cur);
    // 8) three sequential transitions, batched over all 1600 chains (bf16 MFMA)
    for (int j = 0; j < 3; j++) {
        gemmbf(stream, mean_cur, 1024, nullptr, root, 1024, idxj + j * NCHAIN, 1024,
               Wt1, bt1, nullptr, H1, 1024, NCHAIN, 1024, 2048, 1);
        gemmbf(stream, H1, 1024, nullptr, nullptr, 0, nullptr, 1 << 30,
               Wt2, bt2, nullptr, NS + (size_t)j * NCHAIN * HDIM, 1024,
               NCHAIN, 1024, 1024, 0);
        meanupd_kernel<<<NCHAIN * HDIM / 256, 256, 0, stream>>>(
            NS + (size_t)j * NCHAIN * HDIM, root, idxj + j * NCHAIN, mean_cur);
    }
    // 9) action value -> w (bf16 MFMA + fp64 dot + sigmoid)
    gemmbf(stream, rmean, 1024, vidx, mean_cur, 1024, nullptr, 1024,
           Wav1, bav1, nullptr, H1, 1024, NCHAIN, 1024, 2048, 1);
    valdot_kernel<<<NCHAIN, 256, 0, stream>>>(H1, Wav2, bav2, wbuf);
    wsum_kernel<<<1, 64, 0, stream>>>(wbuf, sims, Wsum);
    // 10) acc = (1+Wsum)*root, then sparse corrections (acc lives in d_out)
    accinit_kernel<<<(BATCH * SEQ * HDIM) / 256, 256, 0, stream>>>(root, Wsum, out);
    corrections_kernel<<<BATCH, 1024, 0, stream>>>(NS, root, wbuf, sims, idxj, out);
    // 11) aggregation (bf16 MFMA): h = gelu([root, acc]@Wg1+bg1); out = root + h@Wg2+bg2
    gemmbf(stream, root, 1024, nullptr, out, 1024, nullptr, 1024,
           Wg1, bg1, nullptr, h_buf, 1024, BATCH * SEQ, 1024, 2048, 1);
    gemmbf(stream, h_buf, 1024, nullptr, nullptr, 0, nullptr, 1 << 30,
           Wg2, bg2, root, out, 1024, BATCH * SEQ, 1024, 1024, 0);
}

// Round 7
// 1591.628 us; speedup vs baseline: 4.5382x; 1.9182x over previous
//
#include <hip/hip_runtime.h>
#include <hip/hip_bf16.h>
#include <cstdint>
#include <math.h>

// ---------------------------------------------------------------------------
// AdaptiveMCTSReasoner  B=16, S=1024, H=1024, MAX_SIMS=100, K_FOCUS=3
// Round 7: performance pass.
//  - policy GEMM: 128x128 fp32 tile with FUSED focus-logit dot (fp64 atomics)
//    -> no 64MB h_buf, no separate focus kernel.
//  - bulk GEMMs: m97-style bf16 MFMA: weights pre-transposed to [N][K] bf16,
//    B staged via global_load_lds(16B) w/ inverse-swizzled source, A staged
//    fp32->bf16 reg path w/ XOR-swizzled ds_write; swizzle kills 32-way
//    ds_read_b128 bank conflicts.
//  - controller: dedicated small-M fp64 reduction kernels (occupancy fix).
//  - corrections: parallel over 4800 (t,j,chain) with fp32 atomics.
//  - gumbel/selection path byte-identical to rounds 5/6 (passing).
// ---------------------------------------------------------------------------

#define SEQ 1024
#define BATCH 16
#define HDIM 1024
#define NSIM 100
#define NCHAIN (NSIM * BATCH)   // 1600
#define SHC (SEQ * HDIM)        // batch stride in root

typedef short bf16x8 __attribute__((ext_vector_type(8)));
typedef float f32x4 __attribute__((ext_vector_type(4)));
typedef float float4v __attribute__((ext_vector_type(4)));

__device__ __forceinline__ unsigned short f2bf(float f) {
    union { float f; uint32_t u; } c; c.f = f;
    uint32_t u = c.u;
    return (unsigned short)((u + 0x7FFFu + ((u >> 16) & 1u)) >> 16);   // RNE
}

__device__ __forceinline__ void gll16(const void* g, void* l) {
    __builtin_amdgcn_global_load_lds(
        (const __attribute__((address_space(1))) void*)g,
        (__attribute__((address_space(3))) void*)l, 16, 0, 0);
}

__device__ __forceinline__ float gelu32(float x) {
    return 0.5f * x * (1.0f + erff(x * 0.70710678f));
}

// ------------------------------- threefry ----------------------------------
__device__ __forceinline__ uint32_t rotl32(uint32_t v, int r) {
    return (v << r) | (v >> (32 - r));
}

__device__ __forceinline__ void threefry(uint32_t k0, uint32_t k1,
                                         uint32_t c0, uint32_t c1,
                                         uint32_t& o0, uint32_t& o1) {
    uint32_t ks0 = k0, ks1 = k1, ks2 = k0 ^ k1 ^ 0x1BD11BDAu;
    uint32_t x0 = c0 + ks0, x1 = c1 + ks1;
#define TFR(r) { x0 += x1; x1 = rotl32(x1, r); x1 ^= x0; }
    TFR(13) TFR(15) TFR(26) TFR(6)   x0 += ks1; x1 += ks2 + 1u;
    TFR(17) TFR(29) TFR(16) TFR(24)  x0 += ks2; x1 += ks0 + 2u;
    TFR(13) TFR(15) TFR(26) TFR(6)   x0 += ks0; x1 += ks1 + 3u;
    TFR(17) TFR(29) TFR(16) TFR(24)  x0 += ks1; x1 += ks2 + 4u;
    TFR(13) TFR(15) TFR(26) TFR(6)   x0 += ks2; x1 += ks0 + 5u;
#undef TFR
    o0 = x0; o1 = x1;
}

__device__ __forceinline__ bool better(float va, int ia, float vb, int ib) {
    return (va > vb) || (va == vb && ia < ib);
}

// ----------------- weight transpose+convert: WT[n][k] = bf16(W[k][n]) ------
__global__ __launch_bounds__(256)
void transpose_bf16(const float* __restrict__ W, unsigned short* __restrict__ WT,
                    int K, int N) {
    __shared__ float t[32][33];
    int kb = blockIdx.x * 32, nb = blockIdx.y * 32;
    int tx = threadIdx.x & 31, ty4 = threadIdx.x >> 5;
#pragma unroll
    for (int p = 0; p < 4; ++p) {
        int ky = ty4 + p * 8;
        t[ky][tx] = W[(long)(kb + ky) * N + nb + tx];
    }
    __syncthreads();
#pragma unroll
    for (int p = 0; p < 4; ++p) {
        int ny = ty4 + p * 8;
        WT[(long)(nb + ny) * K + kb + tx] = f2bf(t[tx][ny]);
    }
}

// ------------------------- GEMM (bf16 MFMA, B^T weights) --------------------
// C = act(A @ WT^T + bias)(+Cadd). ABF=0: A fp32 dual-source w/ row-gathers,
// staged with convert+swizzled ds_write. ABF=1: A bf16 dense, staged via gll.
// B always bf16 WT[n][k] via gll with inverse-swizzled source.
// 128x128 tile, BK=64, 4 waves (2x2 of 64x64), mfma_f32_16x16x32_bf16.
template<int ABF>
__global__ __launch_bounds__(256)
void gemm_bt(const void* __restrict__ Av1, long lda1, const int* __restrict__ a1rows,
             const void* __restrict__ Av2, long lda2, const int* __restrict__ a2rows,
             int K1,
             const unsigned short* __restrict__ WT,
             const float* __restrict__ bias,
             const float* __restrict__ Cadd,
             float* __restrict__ C,
             unsigned short* __restrict__ Cbf,
             long ldc, int M, int N, int K, int doGelu) {
    __shared__ unsigned short As[128 * 64];
    __shared__ unsigned short Bs[128 * 64];
    __shared__ int r1s[128], r2s[128];
    int tid = threadIdx.x;
    int row0 = blockIdx.y * 128, col0 = blockIdx.x * 128;
    if (tid < 128) {
        int gm = row0 + tid; if (gm >= M) gm = M - 1;
        r1s[tid] = a1rows ? a1rows[gm] : gm;
        r2s[tid] = a2rows ? a2rows[gm] : gm;
    }
    int wid = tid >> 6, lane = tid & 63;
    int wr = wid >> 1, wc = wid & 1, llo = lane & 15, lhi = lane >> 4;
    f32x4 acc[4][4];
#pragma unroll
    for (int i = 0; i < 4; i++)
#pragma unroll
        for (int j = 0; j < 4; j++) acc[i][j] = (f32x4){0.f, 0.f, 0.f, 0.f};
    __syncthreads();

    char* AsB = (char*)As;
    char* BsB = (char*)Bs;
    for (int k0 = 0; k0 < K; k0 += 64) {
        // ---- B stage: gll, source chunk inverse-swizzled ----
#pragma unroll
        for (int i = 0; i < 4; ++i) {
            int q = tid + (i << 8);
            int r = q >> 3, cs = q & 7, c = cs ^ (r & 7);
            gll16(WT + (long)(col0 + r) * K + (k0 + (c << 3)), BsB + (q << 4));
        }
        // ---- A stage ----
        if (ABF) {
            const unsigned short* Ab = (const unsigned short*)Av1;
#pragma unroll
            for (int i = 0; i < 4; ++i) {
                int q = tid + (i << 8);
                int r = q >> 3, cs = q & 7, c = cs ^ (r & 7);
                gll16(Ab + (long)r1s[r] * lda1 + (k0 + (c << 3)), AsB + (q << 4));
            }
        } else {
            const float* A1f = (const float*)Av1;
            const float* A2f = (const float*)Av2;
            bool s1 = (k0 < K1);
#pragma unroll
            for (int i = 0; i < 4; ++i) {
                int q = tid + (i << 8);
                int r = q >> 3, c = q & 7;
                const float* src = s1 ? (A1f + (long)r1s[r] * lda1 + (k0 + (c << 3)))
                                      : (A2f + (long)r2s[r] * lda2 + (k0 - K1 + (c << 3)));
                float4v v0 = *(const float4v*)src;
                float4v v1 = *(const float4v*)(src + 4);
                bf16x8 s;
                s[0] = (short)f2bf(v0[0]); s[1] = (short)f2bf(v0[1]);
                s[2] = (short)f2bf(v0[2]); s[3] = (short)f2bf(v0[3]);
                s[4] = (short)f2bf(v1[0]); s[5] = (short)f2bf(v1[1]);
                s[6] = (short)f2bf(v1[2]); s[7] = (short)f2bf(v1[3]);
                *(bf16x8*)(AsB + ((r << 7) + ((c ^ (r & 7)) << 4))) = s;
            }
        }
        __syncthreads();
#pragma unroll
        for (int ks = 0; ks < 2; ++ks) {
            bf16x8 af[4], bfv[4];
#pragma unroll
            for (int mt = 0; mt < 4; ++mt) {
                int r = wr * 64 + mt * 16 + llo;
                af[mt] = *(const bf16x8*)(AsB + ((r << 7) + ((((ks << 2) | lhi) ^ (r & 7)) << 4)));
            }
#pragma unroll
            for (int nt = 0; nt < 4; ++nt) {
                int r = wc * 64 + nt * 16 + llo;
                bfv[nt] = *(const bf16x8*)(BsB + ((r << 7) + ((((ks << 2) | lhi) ^ (r & 7)) << 4)));
            }
#pragma unroll
            for (int mt = 0; mt < 4; ++mt)
#pragma unroll
                for (int nt = 0; nt < 4; ++nt)
                    acc[mt][nt] = __builtin_amdgcn_mfma_f32_16x16x32_bf16(
                        af[mt], bfv[nt], acc[mt][nt], 0, 0, 0);
        }
        __syncthreads();
    }
    // epilogue: C/D col=lane&15, row=(lane>>4)*4+reg  [m89-verified]
#pragma unroll
    for (int mt = 0; mt < 4; ++mt) {
#pragma unroll
        for (int nt = 0; nt < 4; ++nt) {
            int gn = col0 + wc * 64 + nt * 16 + llo;
#pragma unroll
            for (int r = 0; r < 4; ++r) {
                int gm = row0 + wr * 64 + mt * 16 + lhi * 4 + r;
                if (gm >= M) continue;
                float v = acc[mt][nt][r] + bias[gn];
                if (doGelu) v = gelu32(v);
                if (Cadd) v += Cadd[(long)gm * ldc + gn];
                if (C)   C[(long)gm * ldc + gn] = v;
                if (Cbf) Cbf[(long)gm * ldc + gn] = f2bf(v);
            }
        }
    }
}

// ---------------- policy GEMM (fp32) with fused focus-logit dot -------------
// x = root@Wp1+bp1 ; fl64[m] += sum_n gelu(x[m,n])*wp2m[n]  (fp64 atomics)
__global__ __launch_bounds__(256)
void policy_fl(const float* __restrict__ root, const float* __restrict__ Wp1,
               const float* __restrict__ bp1, const float* __restrict__ wp2m,
               double* __restrict__ fl64) {
    __shared__ float As[16][136];
    __shared__ float Bs[16][136];
    int tid = threadIdx.x;
    int row0 = blockIdx.y * 128, col0 = blockIdx.x * 128;
    int tx = tid & 15, ty = tid >> 4;
    float acc[8][8] = {};
    for (int k0 = 0; k0 < 1024; k0 += 16) {
#pragma unroll
        for (int i = 0; i < 2; ++i) {
            int e = tid + (i << 8);
            int m = e >> 2, kc = e & 3;
            float4v v = *(const float4v*)&root[(long)(row0 + m) * 1024 + k0 + (kc << 2)];
            As[(kc << 2) + 0][m] = v[0];
            As[(kc << 2) + 1][m] = v[1];
            As[(kc << 2) + 2][m] = v[2];
            As[(kc << 2) + 3][m] = v[3];
        }
#pragma unroll
        for (int i = 0; i < 2; ++i) {
            int e = tid + (i << 8);
            int kk = e >> 5, nc = e & 31;
            *(float4v*)&Bs[kk][nc << 2] =
                *(const float4v*)&Wp1[(long)(k0 + kk) * 1024 + col0 + (nc << 2)];
        }
        __syncthreads();
#pragma unroll
        for (int kk = 0; kk < 16; ++kk) {
            float4v a0 = *(const float4v*)&As[kk][ty << 3];
            float4v a1 = *(const float4v*)&As[kk][(ty << 3) + 4];
            float4v b0 = *(const float4v*)&Bs[kk][tx << 3];
            float4v b1 = *(const float4v*)&Bs[kk][(tx << 3) + 4];
            float av[8] = {a0[0], a0[1], a0[2], a0[3], a1[0], a1[1], a1[2], a1[3]};
            float bv[8] = {b0[0], b0[1], b0[2], b0[3], b1[0], b1[1], b1[2], b1[3]};
#pragma unroll
            for (int ii = 0; ii < 8; ++ii)
#pragma unroll
                for (int jj = 0; jj < 8; ++jj)
                    acc[ii][jj] = fmaf(av[ii], bv[jj], acc[ii][jj]);
        }
        __syncthreads();
    }
    double part[8];
#pragma unroll
    for (int ii = 0; ii < 8; ++ii) part[ii] = 0.0;
#pragma unroll
    for (int ii = 0; ii < 8; ++ii) {
#pragma unroll
        for (int jj = 0; jj < 8; ++jj) {
            int gn = col0 + (tx << 3) + jj;
            float x = acc[ii][jj] + bp1[gn];
            part[ii] += (double)gelu32(x) * (double)wp2m[gn];
        }
    }
#pragma unroll
    for (int ii = 0; ii < 8; ++ii) {
        double v = part[ii];
        v += __shfl_xor(v, 1);
        v += __shfl_xor(v, 2);
        v += __shfl_xor(v, 4);
        v += __shfl_xor(v, 8);
        if (tx == 0) atomicAdd(&fl64[row0 + (ty << 3) + ii], v);
    }
}

__global__ void flbuild_kernel(const double* __restrict__ fl64,
                               const float* __restrict__ wp2m,
                               const int* __restrict__ amask,
                               float* __restrict__ fl32) {
    int m = blockIdx.x * 256 + threadIdx.x;
    fl32[m] = (amask[m] == 0) ? -1e9f : (float)(fl64[m] + (double)wp2m[1024]);
}

// --------------------------- small kernels ---------------------------------
__global__ void wp2mean_kernel(const float* __restrict__ Wp2,
                               const float* __restrict__ bp2,
                               float* __restrict__ outv) {
    __shared__ double sb[256];
    int r = blockIdx.x, tid = threadIdx.x;
    const float* src = (r < 1024) ? (Wp2 + (size_t)r * 1024) : bp2;
    double s = 0.0;
    for (int k = tid; k < 1024; k += 256) s += (double)src[k];
    sb[tid] = s; __syncthreads();
    for (int off = 128; off > 0; off >>= 1) {
        if (tid < off) sb[tid] += sb[tid + off];
        __syncthreads();
    }
    if (tid == 0) outv[r] = (float)(sb[0] * (1.0 / 1024.0));
}

__global__ void rootmean_kernel(const float* __restrict__ root, float* __restrict__ rmean) {
    int b = blockIdx.x;
    int h = blockIdx.y * 256 + threadIdx.x;
    const float* base = root + (size_t)b * SHC + h;
    double s = 0.0;
    for (int ss = 0; ss < SEQ; ss++) s += (double)base[(size_t)ss * HDIM];
    rmean[b * HDIM + h] = (float)(s * (1.0 / 1024.0));
}

// controller fc1: T1[b][n] = gelu64(root[b,0,:]·Wsc1[:,n] + b1[n]); grid 64
__global__ __launch_bounds__(256)
void ctrl_fc1(const float* __restrict__ root, const float* __restrict__ W,
              const float* __restrict__ b1, float* __restrict__ T1) {
    __shared__ double red[16][17];
    int ni = threadIdx.x & 15, kt = threadIdx.x >> 4;
    int n = blockIdx.x * 16 + ni;
    double accb[16];
#pragma unroll
    for (int bb = 0; bb < 16; ++bb) accb[bb] = 0.0;
    for (int k = kt * 64; k < kt * 64 + 64; ++k) {
        double w = (double)W[(long)k * 1024 + n];
#pragma unroll
        for (int bb = 0; bb < 16; ++bb)
            accb[bb] = fma((double)root[(long)bb * SHC + k], w, accb[bb]);
    }
    for (int bb = 0; bb < 16; ++bb) {
        red[kt][ni] = accb[bb];
        __syncthreads();
        if (kt == 0) {
            double s = 0.0;
            for (int q = 0; q < 16; ++q) s += red[q][ni];
            double x = s + (double)b1[n];
            T1[bb * 1024 + n] = (float)(0.5 * x * (1.0 + erf(x * 0.70710678118654752440)));
        }
        __syncthreads();
    }
}

// controller fc2: logits[b][n] (grid 80)
__global__ void ctrl_fc2(const float* __restrict__ T1, const float* __restrict__ W2,
                         const float* __restrict__ b2, float* __restrict__ logits) {
    __shared__ double sb[256];
    int bn = blockIdx.x;
    int b = bn / 5, n = bn % 5;
    double s = 0.0;
    for (int k = threadIdx.x; k < 1024; k += 256)
        s += (double)T1[b * 1024 + k] * (double)W2[k * 5 + n];
    sb[threadIdx.x] = s; __syncthreads();
    for (int off = 128; off > 0; off >>= 1) {
        if (threadIdx.x < off) sb[threadIdx.x] += sb[threadIdx.x + off];
        __syncthreads();
    }
    if (threadIdx.x == 0) logits[b * 5 + n] = (float)(sb[0] + (double)b2[n]);
}

__global__ void sims_kernel(const float* __restrict__ logits, int* __restrict__ sims) {
    int b = threadIdx.x;
    if (b >= BATCH) return;
    float best = logits[b * 5 + 0]; int biv = 0;
    for (int i = 1; i < 5; i++) {
        float v = logits[b * 5 + i];
        if (v > best) { best = v; biv = i; }
    }
    const int opt[5] = {10, 25, 50, 75, 100};
    sims[b] = opt[biv];
}

// Per (t,b): JAX PARTITIONABLE threefry (byte-identical to round 5/6)
__global__ void gumbel_kernel(const float* __restrict__ fl,
                              int* __restrict__ idxj, int* __restrict__ vidx) {
    __shared__ float sv[256][3];
    __shared__ int   si[256][3];
    int blk = blockIdx.x;           // c = t*16+b
    int t = blk >> 4, b = blk & 15;
    uint32_t kk0, kk1;
    threefry(0u, 42u, 0u, (uint32_t)t, kk0, kk1);   // fold_in(key(42), t)
    int tid = threadIdx.x;
    float bv[3] = {-INFINITY, -INFINITY, -INFINITY};
    int   bi[3] = {0x7FFFFFFF, 0x7FFFFFFF, 0x7FFFFFFF};
    for (int s = tid; s < SEQ; s += 256) {
        uint32_t m = (uint32_t)(b * SEQ + s);
        uint32_t y0, y1;
        threefry(kk0, kk1, 0u, m, y0, y1);
        uint32_t bits = y0 ^ y1;
        float f = __uint_as_float((bits >> 9) | 0x3F800000u) - 1.0f;
        float u = fmaxf(1.17549435e-38f, f);
        float l1 = (float)log((double)u);
        float l2 = (float)log(-(double)l1);
        float g  = -l2;
        float val = fl[b * SEQ + s] + g;
        if (better(val, s, bv[2], bi[2])) {
            bv[2] = val; bi[2] = s;
            if (better(bv[2], bi[2], bv[1], bi[1])) {
                float tv = bv[1]; int ti = bi[1];
                bv[1] = bv[2]; bi[1] = bi[2]; bv[2] = tv; bi[2] = ti;
            }
            if (better(bv[1], bi[1], bv[0], bi[0])) {
                float tv = bv[0]; int ti = bi[0];
                bv[0] = bv[1]; bi[0] = bi[1]; bv[1] = tv; bi[1] = ti;
            }
        }
    }
    sv[tid][0] = bv[0]; sv[tid][1] = bv[1]; sv[tid][2] = bv[2];
    si[tid][0] = bi[0]; si[tid][1] = bi[1]; si[tid][2] = bi[2];
    __syncthreads();
    for (int off = 128; off > 0; off >>= 1) {
        if (tid < off) {
            float av[3] = {sv[tid][0], sv[tid][1], sv[tid][2]};
            int   ai[3] = {si[tid][0], si[tid][1], si[tid][2]};
            float cv[3] = {sv[tid + off][0], sv[tid + off][1], sv[tid + off][2]};
            int   ci[3] = {si[tid + off][0], si[tid + off][1], si[tid + off][2]};
            float rv[3]; int ri[3]; int pa = 0, pb = 0;
#pragma unroll
            for (int r = 0; r < 3; r++) {
                if (better(av[pa], ai[pa], cv[pb], ci[pb])) { rv[r] = av[pa]; ri[r] = ai[pa]; pa++; }
                else                                        { rv[r] = cv[pb]; ri[r] = ci[pb]; pb++; }
            }
            sv[tid][0] = rv[0]; sv[tid][1] = rv[1]; sv[tid][2] = rv[2];
            si[tid][0] = ri[0]; si[tid][1] = ri[1]; si[tid][2] = ri[2];
        }
        __syncthreads();
    }
    if (tid == 0) {
        idxj[0 * NCHAIN + blk] = b * SEQ + si[0][0];
        idxj[1 * NCHAIN + blk] = b * SEQ + si[0][1];
        idxj[2 * NCHAIN + blk] = b * SEQ + si[0][2];
        vidx[blk] = b;
    }
}

__global__ void meaninit_kernel(const float* __restrict__ rmean, float* __restrict__ mean_cur) {
    int e = blockIdx.x * 256 + threadIdx.x;
    int c = e >> 10, hh = e & 1023;
    mean_cur[e] = rmean[(c & 15) * HDIM + hh];
}

__global__ void meanupd_kernel(const float* __restrict__ NSj, const float* __restrict__ root,
                               const int* __restrict__ idx, float* __restrict__ mean_cur) {
    int e = blockIdx.x * 256 + threadIdx.x;
    int c = e >> 10, hh = e & 1023;
    int r = idx[c];
    double m = (double)mean_cur[e] +
               ((double)NSj[e] - (double)root[(size_t)r * HDIM + hh]) * (1.0 / 1024.0);
    mean_cur[e] = (float)m;
}

__global__ void valdot_kernel(const float* __restrict__ HV, const float* __restrict__ Wav2,
                              const float* __restrict__ bav2, float* __restrict__ w) {
    __shared__ double sb[256];
    int c = blockIdx.x, tid = threadIdx.x;
    double s = 0.0;
    for (int k = tid; k < HDIM; k += 256) s += (double)HV[(size_t)c * HDIM + k] * (double)Wav2[k];
    sb[tid] = s; __syncthreads();
    for (int off = 128; off > 0; off >>= 1) {
        if (tid < off) sb[tid] += sb[tid + off];
        __syncthreads();
    }
    if (tid == 0) {
        double v = sb[0] + (double)bav2[0];
        w[c] = (float)(1.0 / (1.0 + exp(-v)));
    }
}

__global__ void wsum_kernel(const float* __restrict__ w, const int* __restrict__ sims,
                            double* __restrict__ Wsum) {
    int b = threadIdx.x;
    if (b >= BATCH) return;
    int sb = sims[b];
    double s = 0.0;
    for (int t = 0; t < sb; t++) s += (double)w[t * BATCH + b];
    Wsum[b] = s;
}

__global__ void accinit_kernel(const float* __restrict__ root, const double* __restrict__ Wsum,
                               float* __restrict__ acc) {
    size_t e = (size_t)blockIdx.x * 256 + threadIdx.x;
    int b = (int)(e >> 20);
    acc[e] = (float)((1.0 + Wsum[b]) * (double)root[e]);
}

// parallel corrections: one block per (j, chain); fp32 atomics
__global__ __launch_bounds__(256)
void corrections_atomic(const float* __restrict__ NS, const float* __restrict__ root,
                        const float* __restrict__ w, const int* __restrict__ sims,
                        const int* __restrict__ idxj, float* __restrict__ acc) {
    int blk = blockIdx.x;                // 0..4799
    int j = blk / NCHAIN, c = blk % NCHAIN;
    int b = c & 15, t = c >> 4;
    if (t >= sims[b]) return;
    float wv = w[c];
    int row = idxj[j * NCHAIN + c];
    const float* ns = NS + ((long)j * NCHAIN + c) * 1024;
    const float* rt = root + (long)row * 1024;
    float* ac = acc + (long)row * 1024;
    for (int h = threadIdx.x; h < 1024; h += 256)
        atomicAdd(&ac[h], wv * (ns[h] - rt[h]));
}

// ------------------------------- launch ------------------------------------
extern "C" void kernel_launch(void* const* d_in, const int* in_sizes, int n_in,
                              void* d_out, int out_size, void* d_ws, size_t ws_size,
                              hipStream_t stream) {
    (void)in_sizes; (void)n_in; (void)out_size; (void)ws_size;
    const float* root = (const float*)d_in[0];
    const int*   amask = (const int*)d_in[1];
    const float* Wsc1 = (const float*)d_in[2];  const float* bsc1 = (const float*)d_in[3];
    const float* Wsc2 = (const float*)d_in[4];  const float* bsc2 = (const float*)d_in[5];
    const float* Wp1  = (const float*)d_in[6];  const float* bp1  = (const float*)d_in[7];
    const float* Wp2  = (const float*)d_in[8];  const float* bp2  = (const float*)d_in[9];
    const float* Wt1  = (const float*)d_in[10]; const float* bt1  = (const float*)d_in[11];
    const float* Wt2  = (const float*)d_in[12]; const float* bt2  = (const float*)d_in[13];
    const float* Wav1 = (const float*)d_in[14]; const float* bav1 = (const float*)d_in[15];
    const float* Wav2 = (const float*)d_in[16]; const float* bav2 = (const float*)d_in[17];
    const float* Wg1  = (const float*)d_in[18]; const float* bg1  = (const float*)d_in[19];
    const float* Wg2  = (const float*)d_in[20]; const float* bg2  = (const float*)d_in[21];
    float* out = (float*)d_out;

    // ---- workspace carving (~53 MB) ----
    char* p = (char*)d_ws;
    auto carve = [&](size_t nbytes) -> void* {
        void* r = (void*)p; p += (nbytes + 255) & ~(size_t)255; return r;
    };
    // region R (lifetimes: mean_cur/H1bf/Hav/NS die before agg1; h_bf aliases R)
    float*          mean_cur = (float*)carve((size_t)NCHAIN * HDIM * 4);        // 6.55 MB
    unsigned short* H1bf     = (unsigned short*)carve((size_t)NCHAIN * HDIM * 2); // 3.28 MB
    float*          Hav      = (float*)carve((size_t)NCHAIN * HDIM * 4);        // 6.55 MB
    float*          NS       = (float*)carve((size_t)3 * NCHAIN * HDIM * 4);    // 19.7 MB
    unsigned short* h_bf     = (unsigned short*)mean_cur;  // 33.55 MB ≤ 36.0 MB region
    // weights bf16 [N][K]
    unsigned short* WTt1  = (unsigned short*)carve((size_t)1024 * 2048 * 2);
    unsigned short* WTt2  = (unsigned short*)carve((size_t)1024 * 1024 * 2);
    unsigned short* WTav1 = (unsigned short*)carve((size_t)1024 * 2048 * 2);
    unsigned short* WTg1  = (unsigned short*)carve((size_t)1024 * 2048 * 2);
    unsigned short* WTg2  = (unsigned short*)carve((size_t)1024 * 1024 * 2);
    // smalls
    float*  rmean  = (float*)carve(BATCH * HDIM * 4);
    float*  T1     = (float*)carve(BATCH * HDIM * 4);
    float*  logits = (float*)carve(128 * 4);
    float*  wp2m   = (float*)carve(1040 * 4);
    double* fl64   = (double*)carve((size_t)BATCH * SEQ * 8);
    float*  fl32   = (float*)carve(BATCH * SEQ * 4);
    float*  wbuf   = (float*)carve(NCHAIN * 4);
    double* Wsumd  = (double*)carve(64 * 8);
    int*    sims   = (int*)carve(64 * 4);
    int*    idxj   = (int*)carve(3 * NCHAIN * 4);
    int*    vidx   = (int*)carve(NCHAIN * 4);

    // 1) weight transpose+convert to bf16 [N][K]
    transpose_bf16<<<dim3(2048 / 32, 1024 / 32), 256, 0, stream>>>(Wt1, WTt1, 2048, 1024);
    transpose_bf16<<<dim3(1024 / 32, 1024 / 32), 256, 0, stream>>>(Wt2, WTt2, 1024, 1024);
    transpose_bf16<<<dim3(2048 / 32, 1024 / 32), 256, 0, stream>>>(Wav1, WTav1, 2048, 1024);
    transpose_bf16<<<dim3(2048 / 32, 1024 / 32), 256, 0, stream>>>(Wg1, WTg1, 2048, 1024);
    transpose_bf16<<<dim3(1024 / 32, 1024 / 32), 256, 0, stream>>>(Wg2, WTg2, 1024, 1024);
    // 2) wp2 means, root mean
    wp2mean_kernel<<<1025, 256, 0, stream>>>(Wp2, bp2, wp2m);
    rootmean_kernel<<<dim3(BATCH, HDIM / 256), 256, 0, stream>>>(root, rmean);
    // 3) controller (fp64) -> sims
    ctrl_fc1<<<64, 256, 0, stream>>>(root, Wsc1, bsc1, T1);
    ctrl_fc2<<<80, 256, 0, stream>>>(T1, Wsc2, bsc2, logits);
    sims_kernel<<<1, 64, 0, stream>>>(logits, sims);
    // 4) policy + fused focus logits
    hipMemsetAsync(fl64, 0, (size_t)BATCH * SEQ * 8, stream);
    policy_fl<<<dim3(8, 128), 256, 0, stream>>>(root, Wp1, bp1, wp2m, fl64);
    flbuild_kernel<<<BATCH * SEQ / 256, 256, 0, stream>>>(fl64, wp2m, amask, fl32);
    // 5) gumbel top-3 (partitionable threefry, unchanged)
    gumbel_kernel<<<NCHAIN, 256, 0, stream>>>(fl32, idxj, vidx);
    // 6) transitions (sequential over j, batched over 1600 chains)
    meaninit_kernel<<<NCHAIN * HDIM / 256, 256, 0, stream>>>(rmean, mean_cur);
    for (int j = 0; j < 3; j++) {
        gemm_bt<0><<<dim3(8, 13), 256, 0, stream>>>(
            mean_cur, 1024, nullptr, root, 1024, idxj + j * NCHAIN, 1024,
            WTt1, bt1, nullptr, nullptr, H1bf, 1024, NCHAIN, 1024, 2048, 1);
        gemm_bt<1><<<dim3(8, 13), 256, 0, stream>>>(
            H1bf, 1024, nullptr, nullptr, 0, nullptr, 1 << 30,
            WTt2, bt2, nullptr, NS + (size_t)j * NCHAIN * HDIM, nullptr,
            1024, NCHAIN, 1024, 1024, 0);
        meanupd_kernel<<<NCHAIN * HDIM / 256, 256, 0, stream>>>(
            NS + (size_t)j * NCHAIN * HDIM, root, idxj + j * NCHAIN, mean_cur);
    }
    // 7) action value -> w -> Wsum
    gemm_bt<0><<<dim3(8, 13), 256, 0, stream>>>(
        rmean, 1024, vidx, mean_cur, 1024, nullptr, 1024,
        WTav1, bav1, nullptr, Hav, nullptr, 1024, NCHAIN, 1024, 2048, 1);
    valdot_kernel<<<NCHAIN, 256, 0, stream>>>(Hav, Wav2, bav2, wbuf);
    wsum_kernel<<<1, 64, 0, stream>>>(wbuf, sims, Wsumd);
    // 8) acc (in d_out): init + parallel corrections
    accinit_kernel<<<(BATCH * SEQ * HDIM) / 256, 256, 0, stream>>>(root, Wsumd, out);
    corrections_atomic<<<3 * NCHAIN, 256, 0, stream>>>(NS, root, wbuf, sims, idxj, out);
    // 9) aggregation: h_bf = bf16(gelu([root|acc]@Wg1+bg1)); out = root + h@Wg2+bg2
    gemm_bt<0><<<dim3(8, 128), 256, 0, stream>>>(
        root, 1024, nullptr, out, 1024, nullptr, 1024,
        WTg1, bg1, nullptr, nullptr, h_bf, 1024, BATCH * SEQ, 1024, 2048, 1);
    gemm_bt<1><<<dim3(8, 128), 256, 0, stream>>>(
        h_bf, 1024, nullptr, nullptr, 0, nullptr, 1 << 30,
        WTg2, bg2, root, out, nullptr, 1024, BATCH * SEQ, 1024, 1024, 0);
}

// Round 8
// 991.545 us; speedup vs baseline: 7.2848x; 1.6052x over previous
//
#include <hip/hip_runtime.h>
#include <hip/hip_bf16.h>
#include <cstdint>
#include <math.h>

// ---------------------------------------------------------------------------
// AdaptiveMCTSReasoner  B=16, S=1024, H=1024, MAX_SIMS=100, K_FOCUS=3
// Round 8:
//  - policy GEMM -> bf16x3 MFMA (hi/lo split of A and W; drop lo*lo term,
//    residual ~2^-18 rel < fp32 reorder noise) with fused fl epilogue.
//  - small-M GEMMs (transitions, av1) -> TM=64 tile variant (2x blocks).
//  - everything else unchanged from round 7 (passing, absmax 0.5).
// ---------------------------------------------------------------------------

#define SEQ 1024
#define BATCH 16
#define HDIM 1024
#define NSIM 100
#define NCHAIN (NSIM * BATCH)   // 1600
#define SHC (SEQ * HDIM)

typedef short bf16x8 __attribute__((ext_vector_type(8)));
typedef float f32x4 __attribute__((ext_vector_type(4)));
typedef float float4v __attribute__((ext_vector_type(4)));

__device__ __forceinline__ unsigned short f2bf(float f) {
    union { float f; uint32_t u; } c; c.f = f;
    uint32_t u = c.u;
    return (unsigned short)((u + 0x7FFFu + ((u >> 16) & 1u)) >> 16);   // RNE
}
__device__ __forceinline__ float bf2f(unsigned short h) {
    union { uint32_t u; float f; } c; c.u = ((uint32_t)h) << 16;
    return c.f;
}

__device__ __forceinline__ void gll16(const void* g, void* l) {
    __builtin_amdgcn_global_load_lds(
        (const __attribute__((address_space(1))) void*)g,
        (__attribute__((address_space(3))) void*)l, 16, 0, 0);
}

__device__ __forceinline__ float gelu32(float x) {
    return 0.5f * x * (1.0f + erff(x * 0.70710678f));
}

// ------------------------------- threefry ----------------------------------
__device__ __forceinline__ uint32_t rotl32(uint32_t v, int r) {
    return (v << r) | (v >> (32 - r));
}

__device__ __forceinline__ void threefry(uint32_t k0, uint32_t k1,
                                         uint32_t c0, uint32_t c1,
                                         uint32_t& o0, uint32_t& o1) {
    uint32_t ks0 = k0, ks1 = k1, ks2 = k0 ^ k1 ^ 0x1BD11BDAu;
    uint32_t x0 = c0 + ks0, x1 = c1 + ks1;
#define TFR(r) { x0 += x1; x1 = rotl32(x1, r); x1 ^= x0; }
    TFR(13) TFR(15) TFR(26) TFR(6)   x0 += ks1; x1 += ks2 + 1u;
    TFR(17) TFR(29) TFR(16) TFR(24)  x0 += ks2; x1 += ks0 + 2u;
    TFR(13) TFR(15) TFR(26) TFR(6)   x0 += ks0; x1 += ks1 + 3u;
    TFR(17) TFR(29) TFR(16) TFR(24)  x0 += ks1; x1 += ks2 + 4u;
    TFR(13) TFR(15) TFR(26) TFR(6)   x0 += ks2; x1 += ks0 + 5u;
#undef TFR
    o0 = x0; o1 = x1;
}

__device__ __forceinline__ bool better(float va, int ia, float vb, int ib) {
    return (va > vb) || (va == vb && ia < ib);
}

// ----------------- weight transpose+convert: WT[n][k] = bf16(W[k][n]) ------
__global__ __launch_bounds__(256)
void transpose_bf16(const float* __restrict__ W, unsigned short* __restrict__ WT,
                    int K, int N) {
    __shared__ float t[32][33];
    int kb = blockIdx.x * 32, nb = blockIdx.y * 32;
    int tx = threadIdx.x & 31, ty4 = threadIdx.x >> 5;
#pragma unroll
    for (int p = 0; p < 4; ++p) {
        int ky = ty4 + p * 8;
        t[ky][tx] = W[(long)(kb + ky) * N + nb + tx];
    }
    __syncthreads();
#pragma unroll
    for (int p = 0; p < 4; ++p) {
        int ny = ty4 + p * 8;
        WT[(long)(nb + ny) * K + kb + tx] = f2bf(t[tx][ny]);
    }
}

// hi/lo split transpose for Wp1
__global__ __launch_bounds__(256)
void transpose_split(const float* __restrict__ W, unsigned short* __restrict__ Whi,
                     unsigned short* __restrict__ Wlo, int K, int N) {
    __shared__ float t[32][33];
    int kb = blockIdx.x * 32, nb = blockIdx.y * 32;
    int tx = threadIdx.x & 31, ty4 = threadIdx.x >> 5;
#pragma unroll
    for (int p = 0; p < 4; ++p) {
        int ky = ty4 + p * 8;
        t[ky][tx] = W[(long)(kb + ky) * N + nb + tx];
    }
    __syncthreads();
#pragma unroll
    for (int p = 0; p < 4; ++p) {
        int ny = ty4 + p * 8;
        float w = t[tx][ny];
        unsigned short h = f2bf(w);
        Whi[(long)(nb + ny) * K + kb + tx] = h;
        Wlo[(long)(nb + ny) * K + kb + tx] = f2bf(w - bf2f(h));
    }
}

// ------------------------- GEMM (bf16 MFMA, B^T weights) --------------------
// TM = tile rows (128 or 64). 4 waves as 2x2; wave tile (TM/2) x 64.
template<int ABF, int TM>
__global__ __launch_bounds__(256)
void gemm_bt(const void* __restrict__ Av1, long lda1, const int* __restrict__ a1rows,
             const void* __restrict__ Av2, long lda2, const int* __restrict__ a2rows,
             int K1,
             const unsigned short* __restrict__ WT,
             const float* __restrict__ bias,
             const float* __restrict__ Cadd,
             float* __restrict__ C,
             unsigned short* __restrict__ Cbf,
             long ldc, int M, int N, int K, int doGelu) {
    constexpr int MT = TM / 32;          // row-frags per wave
    constexpr int WROWS = TM / 2;
    __shared__ unsigned short As[TM * 64];
    __shared__ unsigned short Bs[128 * 64];
    __shared__ int r1s[TM], r2s[TM];
    int tid = threadIdx.x;
    int row0 = blockIdx.y * TM, col0 = blockIdx.x * 128;
    if (tid < TM) {
        int gm = row0 + tid; if (gm >= M) gm = M - 1;
        r1s[tid] = a1rows ? a1rows[gm] : gm;
        r2s[tid] = a2rows ? a2rows[gm] : gm;
    }
    int wid = tid >> 6, lane = tid & 63;
    int wr = wid >> 1, wc = wid & 1, llo = lane & 15, lhi = lane >> 4;
    f32x4 acc[MT][4];
#pragma unroll
    for (int i = 0; i < MT; i++)
#pragma unroll
        for (int j = 0; j < 4; j++) acc[i][j] = (f32x4){0.f, 0.f, 0.f, 0.f};
    __syncthreads();

    char* AsB = (char*)As;
    char* BsB = (char*)Bs;
    for (int k0 = 0; k0 < K; k0 += 64) {
        // ---- B stage: gll, source chunk inverse-swizzled ----
#pragma unroll
        for (int i = 0; i < 4; ++i) {
            int q = tid + (i << 8);
            int r = q >> 3, cs = q & 7, c = cs ^ (r & 7);
            gll16(WT + (long)(col0 + r) * K + (k0 + (c << 3)), BsB + (q << 4));
        }
        // ---- A stage ----
        if (ABF) {
            const unsigned short* Ab = (const unsigned short*)Av1;
#pragma unroll
            for (int i = 0; i < MT; ++i) {
                int q = tid + (i << 8);
                int r = q >> 3, cs = q & 7, c = cs ^ (r & 7);
                gll16(Ab + (long)r1s[r] * lda1 + (k0 + (c << 3)), AsB + (q << 4));
            }
        } else {
            const float* A1f = (const float*)Av1;
            const float* A2f = (const float*)Av2;
            bool s1 = (k0 < K1);
#pragma unroll
            for (int i = 0; i < MT; ++i) {
                int q = tid + (i << 8);
                int r = q >> 3, c = q & 7;
                const float* src = s1 ? (A1f + (long)r1s[r] * lda1 + (k0 + (c << 3)))
                                      : (A2f + (long)r2s[r] * lda2 + (k0 - K1 + (c << 3)));
                float4v v0 = *(const float4v*)src;
                float4v v1 = *(const float4v*)(src + 4);
                bf16x8 s;
                s[0] = (short)f2bf(v0[0]); s[1] = (short)f2bf(v0[1]);
                s[2] = (short)f2bf(v0[2]); s[3] = (short)f2bf(v0[3]);
                s[4] = (short)f2bf(v1[0]); s[5] = (short)f2bf(v1[1]);
                s[6] = (short)f2bf(v1[2]); s[7] = (short)f2bf(v1[3]);
                *(bf16x8*)(AsB + ((r << 7) + ((c ^ (r & 7)) << 4))) = s;
            }
        }
        __syncthreads();
#pragma unroll
        for (int ks = 0; ks < 2; ++ks) {
            bf16x8 af[MT], bfv[4];
#pragma unroll
            for (int mt = 0; mt < MT; ++mt) {
                int r = wr * WROWS + mt * 16 + llo;
                af[mt] = *(const bf16x8*)(AsB + ((r << 7) + ((((ks << 2) | lhi) ^ (r & 7)) << 4)));
            }
#pragma unroll
            for (int nt = 0; nt < 4; ++nt) {
                int r = wc * 64 + nt * 16 + llo;
                bfv[nt] = *(const bf16x8*)(BsB + ((r << 7) + ((((ks << 2) | lhi) ^ (r & 7)) << 4)));
            }
#pragma unroll
            for (int mt = 0; mt < MT; ++mt)
#pragma unroll
                for (int nt = 0; nt < 4; ++nt)
                    acc[mt][nt] = __builtin_amdgcn_mfma_f32_16x16x32_bf16(
                        af[mt], bfv[nt], acc[mt][nt], 0, 0, 0);
        }
        __syncthreads();
    }
    // epilogue: C/D col=lane&15, row=(lane>>4)*4+reg  [m89-verified]
#pragma unroll
    for (int mt = 0; mt < MT; ++mt) {
#pragma unroll
        for (int nt = 0; nt < 4; ++nt) {
            int gn = col0 + wc * 64 + nt * 16 + llo;
#pragma unroll
            for (int r = 0; r < 4; ++r) {
                int gm = row0 + wr * WROWS + mt * 16 + lhi * 4 + r;
                if (gm >= M) continue;
                float v = acc[mt][nt][r] + bias[gn];
                if (doGelu) v = gelu32(v);
                if (Cadd) v += Cadd[(long)gm * ldc + gn];
                if (C)   C[(long)gm * ldc + gn] = v;
                if (Cbf) Cbf[(long)gm * ldc + gn] = f2bf(v);
            }
        }
    }
}

// ---------------- policy: bf16x3 MFMA GEMM with fused focus-logit dot -------
// x = root@Wp1+bp1 via Ahi*Whi + Ahi*Wlo + Alo*Whi (lo*lo dropped, ~2^-18 rel)
// fl64[m] += sum_n gelu(x[m,n])*wp2m[n]  (fp64 atomics)
__global__ __launch_bounds__(256)
void policy_bf16x3(const float* __restrict__ root,
                   const unsigned short* __restrict__ Whi,
                   const unsigned short* __restrict__ Wlo,
                   const float* __restrict__ bp1, const float* __restrict__ wp2m,
                   double* __restrict__ fl64) {
    __shared__ unsigned short Ahi[128 * 64], Alo[128 * 64];
    __shared__ unsigned short Bhi[128 * 64], Blo[128 * 64];
    int tid = threadIdx.x;
    int row0 = blockIdx.y * 128, col0 = blockIdx.x * 128;
    int wid = tid >> 6, lane = tid & 63;
    int wr = wid >> 1, wc = wid & 1, llo = lane & 15, lhi = lane >> 4;
    f32x4 acc[4][4];
#pragma unroll
    for (int i = 0; i < 4; i++)
#pragma unroll
        for (int j = 0; j < 4; j++) acc[i][j] = (f32x4){0.f, 0.f, 0.f, 0.f};

    char* AhB = (char*)Ahi; char* AlB = (char*)Alo;
    char* BhB = (char*)Bhi; char* BlB = (char*)Blo;
    for (int k0 = 0; k0 < 1024; k0 += 64) {
        // B stage: both splits via gll, inverse-swizzled source
#pragma unroll
        for (int i = 0; i < 4; ++i) {
            int q = tid + (i << 8);
            int r = q >> 3, cs = q & 7, c = cs ^ (r & 7);
            long off = (long)(col0 + r) * 1024 + (k0 + (c << 3));
            gll16(Whi + off, BhB + (q << 4));
            gll16(Wlo + off, BlB + (q << 4));
        }
        // A stage: read fp32, split hi/lo, swizzled ds_write
#pragma unroll
        for (int i = 0; i < 4; ++i) {
            int q = tid + (i << 8);
            int r = q >> 3, c = q & 7;
            const float* src = root + (long)(row0 + r) * 1024 + (k0 + (c << 3));
            float4v v0 = *(const float4v*)src;
            float4v v1 = *(const float4v*)(src + 4);
            bf16x8 sh, sl;
#pragma unroll
            for (int e = 0; e < 4; ++e) {
                unsigned short h0 = f2bf(v0[e]);
                sh[e] = (short)h0; sl[e] = (short)f2bf(v0[e] - bf2f(h0));
                unsigned short h1 = f2bf(v1[e]);
                sh[e + 4] = (short)h1; sl[e + 4] = (short)f2bf(v1[e] - bf2f(h1));
            }
            int off = (r << 7) + ((c ^ (r & 7)) << 4);
            *(bf16x8*)(AhB + off) = sh;
            *(bf16x8*)(AlB + off) = sl;
        }
        __syncthreads();
#pragma unroll
        for (int ks = 0; ks < 2; ++ks) {
            bf16x8 ah[4], al[4], bh[4], bl[4];
#pragma unroll
            for (int mt = 0; mt < 4; ++mt) {
                int r = wr * 64 + mt * 16 + llo;
                int off = (r << 7) + ((((ks << 2) | lhi) ^ (r & 7)) << 4);
                ah[mt] = *(const bf16x8*)(AhB + off);
                al[mt] = *(const bf16x8*)(AlB + off);
            }
#pragma unroll
            for (int nt = 0; nt < 4; ++nt) {
                int r = wc * 64 + nt * 16 + llo;
                int off = (r << 7) + ((((ks << 2) | lhi) ^ (r & 7)) << 4);
                bh[nt] = *(const bf16x8*)(BhB + off);
                bl[nt] = *(const bf16x8*)(BlB + off);
            }
#pragma unroll
            for (int mt = 0; mt < 4; ++mt)
#pragma unroll
                for (int nt = 0; nt < 4; ++nt) {
                    acc[mt][nt] = __builtin_amdgcn_mfma_f32_16x16x32_bf16(
                        ah[mt], bh[nt], acc[mt][nt], 0, 0, 0);
                    acc[mt][nt] = __builtin_amdgcn_mfma_f32_16x16x32_bf16(
                        ah[mt], bl[nt], acc[mt][nt], 0, 0, 0);
                    acc[mt][nt] = __builtin_amdgcn_mfma_f32_16x16x32_bf16(
                        al[mt], bh[nt], acc[mt][nt], 0, 0, 0);
                }
        }
        __syncthreads();
    }
    // epilogue: per-lane row partials (double), reduce over llo, atomicAdd
#pragma unroll
    for (int mt = 0; mt < 4; ++mt) {
        double part[4] = {0.0, 0.0, 0.0, 0.0};
#pragma unroll
        for (int nt = 0; nt < 4; ++nt) {
            int gn = col0 + wc * 64 + nt * 16 + llo;
            float b = bp1[gn], wn = wp2m[gn];
#pragma unroll
            for (int r = 0; r < 4; ++r) {
                float x = acc[mt][nt][r] + b;
                part[r] += (double)gelu32(x) * (double)wn;
            }
        }
#pragma unroll
        for (int r = 0; r < 4; ++r) {
            double v = part[r];
            v += __shfl_xor(v, 1);
            v += __shfl_xor(v, 2);
            v += __shfl_xor(v, 4);
            v += __shfl_xor(v, 8);
            if (llo == 0)
                atomicAdd(&fl64[row0 + wr * 64 + mt * 16 + lhi * 4 + r], v);
        }
    }
}

__global__ void flbuild_kernel(const double* __restrict__ fl64,
                               const float* __restrict__ wp2m,
                               const int* __restrict__ amask,
                               float* __restrict__ fl32) {
    int m = blockIdx.x * 256 + threadIdx.x;
    fl32[m] = (amask[m] == 0) ? -1e9f : (float)(fl64[m] + (double)wp2m[1024]);
}

// --------------------------- small kernels ---------------------------------
__global__ void wp2mean_kernel(const float* __restrict__ Wp2,
                               const float* __restrict__ bp2,
                               float* __restrict__ outv) {
    __shared__ double sb[256];
    int r = blockIdx.x, tid = threadIdx.x;
    const float* src = (r < 1024) ? (Wp2 + (size_t)r * 1024) : bp2;
    double s = 0.0;
    for (int k = tid; k < 1024; k += 256) s += (double)src[k];
    sb[tid] = s; __syncthreads();
    for (int off = 128; off > 0; off >>= 1) {
        if (tid < off) sb[tid] += sb[tid + off];
        __syncthreads();
    }
    if (tid == 0) outv[r] = (float)(sb[0] * (1.0 / 1024.0));
}

__global__ void rootmean_kernel(const float* __restrict__ root, float* __restrict__ rmean) {
    int b = blockIdx.x;
    int h = blockIdx.y * 256 + threadIdx.x;
    const float* base = root + (size_t)b * SHC + h;
    double s = 0.0;
    for (int ss = 0; ss < SEQ; ss++) s += (double)base[(size_t)ss * HDIM];
    rmean[b * HDIM + h] = (float)(s * (1.0 / 1024.0));
}

__global__ __launch_bounds__(256)
void ctrl_fc1(const float* __restrict__ root, const float* __restrict__ W,
              const float* __restrict__ b1, float* __restrict__ T1) {
    __shared__ double red[16][17];
    int ni = threadIdx.x & 15, kt = threadIdx.x >> 4;
    int n = blockIdx.x * 16 + ni;
    double accb[16];
#pragma unroll
    for (int bb = 0; bb < 16; ++bb) accb[bb] = 0.0;
    for (int k = kt * 64; k < kt * 64 + 64; ++k) {
        double w = (double)W[(long)k * 1024 + n];
#pragma unroll
        for (int bb = 0; bb < 16; ++bb)
            accb[bb] = fma((double)root[(long)bb * SHC + k], w, accb[bb]);
    }
    for (int bb = 0; bb < 16; ++bb) {
        red[kt][ni] = accb[bb];
        __syncthreads();
        if (kt == 0) {
            double s = 0.0;
            for (int q = 0; q < 16; ++q) s += red[q][ni];
            double x = s + (double)b1[n];
            T1[bb * 1024 + n] = (float)(0.5 * x * (1.0 + erf(x * 0.70710678118654752440)));
        }
        __syncthreads();
    }
}

__global__ void ctrl_fc2(const float* __restrict__ T1, const float* __restrict__ W2,
                         const float* __restrict__ b2, float* __restrict__ logits) {
    __shared__ double sb[256];
    int bn = blockIdx.x;
    int b = bn / 5, n = bn % 5;
    double s = 0.0;
    for (int k = threadIdx.x; k < 1024; k += 256)
        s += (double)T1[b * 1024 + k] * (double)W2[k * 5 + n];
    sb[threadIdx.x] = s; __syncthreads();
    for (int off = 128; off > 0; off >>= 1) {
        if (threadIdx.x < off) sb[threadIdx.x] += sb[threadIdx.x + off];
        __syncthreads();
    }
    if (threadIdx.x == 0) logits[b * 5 + n] = (float)(sb[0] + (double)b2[n]);
}

__global__ void sims_kernel(const float* __restrict__ logits, int* __restrict__ sims) {
    int b = threadIdx.x;
    if (b >= BATCH) return;
    float best = logits[b * 5 + 0]; int biv = 0;
    for (int i = 1; i < 5; i++) {
        float v = logits[b * 5 + i];
        if (v > best) { best = v; biv = i; }
    }
    const int opt[5] = {10, 25, 50, 75, 100};
    sims[b] = opt[biv];
}

// Per (t,b): JAX PARTITIONABLE threefry (byte-identical to rounds 5-7)
__global__ void gumbel_kernel(const float* __restrict__ fl,
                              int* __restrict__ idxj, int* __restrict__ vidx) {
    __shared__ float sv[256][3];
    __shared__ int   si[256][3];
    int blk = blockIdx.x;           // c = t*16+b
    int t = blk >> 4, b = blk & 15;
    uint32_t kk0, kk1;
    threefry(0u, 42u, 0u, (uint32_t)t, kk0, kk1);   // fold_in(key(42), t)
    int tid = threadIdx.x;
    float bv[3] = {-INFINITY, -INFINITY, -INFINITY};
    int   bi[3] = {0x7FFFFFFF, 0x7FFFFFFF, 0x7FFFFFFF};
    for (int s = tid; s < SEQ; s += 256) {
        uint32_t m = (uint32_t)(b * SEQ + s);
        uint32_t y0, y1;
        threefry(kk0, kk1, 0u, m, y0, y1);
        uint32_t bits = y0 ^ y1;
        float f = __uint_as_float((bits >> 9) | 0x3F800000u) - 1.0f;
        float u = fmaxf(1.17549435e-38f, f);
        float l1 = (float)log((double)u);
        float l2 = (float)log(-(double)l1);
        float g  = -l2;
        float val = fl[b * SEQ + s] + g;
        if (better(val, s, bv[2], bi[2])) {
            bv[2] = val; bi[2] = s;
            if (better(bv[2], bi[2], bv[1], bi[1])) {
                float tv = bv[1]; int ti = bi[1];
                bv[1] = bv[2]; bi[1] = bi[2]; bv[2] = tv; bi[2] = ti;
            }
            if (better(bv[1], bi[1], bv[0], bi[0])) {
                float tv = bv[0]; int ti = bi[0];
                bv[0] = bv[1]; bi[0] = bi[1]; bv[1] = tv; bi[1] = ti;
            }
        }
    }
    sv[tid][0] = bv[0]; sv[tid][1] = bv[1]; sv[tid][2] = bv[2];
    si[tid][0] = bi[0]; si[tid][1] = bi[1]; si[tid][2] = bi[2];
    __syncthreads();
    for (int off = 128; off > 0; off >>= 1) {
        if (tid < off) {
            float av[3] = {sv[tid][0], sv[tid][1], sv[tid][2]};
            int   ai[3] = {si[tid][0], si[tid][1], si[tid][2]};
            float cv[3] = {sv[tid + off][0], sv[tid + off][1], sv[tid + off][2]};
            int   ci[3] = {si[tid + off][0], si[tid + off][1], si[tid + off][2]};
            float rv[3]; int ri[3]; int pa = 0, pb = 0;
#pragma unroll
            for (int r = 0; r < 3; r++) {
                if (better(av[pa], ai[pa], cv[pb], ci[pb])) { rv[r] = av[pa]; ri[r] = ai[pa]; pa++; }
                else                                        { rv[r] = cv[pb]; ri[r] = ci[pb]; pb++; }
            }
            sv[tid][0] = rv[0]; sv[tid][1] = rv[1]; sv[tid][2] = rv[2];
            si[tid][0] = ri[0]; si[tid][1] = ri[1]; si[tid][2] = ri[2];
        }
        __syncthreads();
    }
    if (tid == 0) {
        idxj[0 * NCHAIN + blk] = b * SEQ + si[0][0];
        idxj[1 * NCHAIN + blk] = b * SEQ + si[0][1];
        idxj[2 * NCHAIN + blk] = b * SEQ + si[0][2];
        vidx[blk] = b;
    }
}

__global__ void meaninit_kernel(const float* __restrict__ rmean, float* __restrict__ mean_cur) {
    int e = blockIdx.x * 256 + threadIdx.x;
    int c = e >> 10, hh = e & 1023;
    mean_cur[e] = rmean[(c & 15) * HDIM + hh];
}

__global__ void meanupd_kernel(const float* __restrict__ NSj, const float* __restrict__ root,
                               const int* __restrict__ idx, float* __restrict__ mean_cur) {
    int e = blockIdx.x * 256 + threadIdx.x;
    int c = e >> 10, hh = e & 1023;
    int r = idx[c];
    double m = (double)mean_cur[e] +
               ((double)NSj[e] - (double)root[(size_t)r * HDIM + hh]) * (1.0 / 1024.0);
    mean_cur[e] = (float)m;
}

__global__ void valdot_kernel(const float* __restrict__ HV, const float* __restrict__ Wav2,
                              const float* __restrict__ bav2, float* __restrict__ w) {
    __shared__ double sb[256];
    int c = blockIdx.x, tid = threadIdx.x;
    double s = 0.0;
    for (int k = tid; k < HDIM; k += 256) s += (double)HV[(size_t)c * HDIM + k] * (double)Wav2[k];
    sb[tid] = s; __syncthreads();
    for (int off = 128; off > 0; off >>= 1) {
        if (tid < off) sb[tid] += sb[tid + off];
        __syncthreads();
    }
    if (tid == 0) {
        double v = sb[0] + (double)bav2[0];
        w[c] = (float)(1.0 / (1.0 + exp(-v)));
    }
}

__global__ void wsum_kernel(const float* __restrict__ w, const int* __restrict__ sims,
                            double* __restrict__ Wsum) {
    int b = threadIdx.x;
    if (b >= BATCH) return;
    int sb = sims[b];
    double s = 0.0;
    for (int t = 0; t < sb; t++) s += (double)w[t * BATCH + b];
    Wsum[b] = s;
}

__global__ void accinit_kernel(const float* __restrict__ root, const double* __restrict__ Wsum,
                               float* __restrict__ acc) {
    size_t e = (size_t)blockIdx.x * 256 + threadIdx.x;
    int b = (int)(e >> 20);
    acc[e] = (float)((1.0 + Wsum[b]) * (double)root[e]);
}

__global__ __launch_bounds__(256)
void corrections_atomic(const float* __restrict__ NS, const float* __restrict__ root,
                        const float* __restrict__ w, const int* __restrict__ sims,
                        const int* __restrict__ idxj, float* __restrict__ acc) {
    int blk = blockIdx.x;                // 0..4799
    int j = blk / NCHAIN, c = blk % NCHAIN;
    int b = c & 15, t = c >> 4;
    if (t >= sims[b]) return;
    float wv = w[c];
    int row = idxj[j * NCHAIN + c];
    const float* ns = NS + ((long)j * NCHAIN + c) * 1024;
    const float* rt = root + (long)row * 1024;
    float* ac = acc + (long)row * 1024;
    for (int h = threadIdx.x; h < 1024; h += 256)
        atomicAdd(&ac[h], wv * (ns[h] - rt[h]));
}

// ------------------------------- launch ------------------------------------
extern "C" void kernel_launch(void* const* d_in, const int* in_sizes, int n_in,
                              void* d_out, int out_size, void* d_ws, size_t ws_size,
                              hipStream_t stream) {
    (void)in_sizes; (void)n_in; (void)out_size; (void)ws_size;
    const float* root = (const float*)d_in[0];
    const int*   amask = (const int*)d_in[1];
    const float* Wsc1 = (const float*)d_in[2];  const float* bsc1 = (const float*)d_in[3];
    const float* Wsc2 = (const float*)d_in[4];  const float* bsc2 = (const float*)d_in[5];
    const float* Wp1  = (const float*)d_in[6];  const float* bp1  = (const float*)d_in[7];
    const float* Wp2  = (const float*)d_in[8];  const float* bp2  = (const float*)d_in[9];
    const float* Wt1  = (const float*)d_in[10]; const float* bt1  = (const float*)d_in[11];
    const float* Wt2  = (const float*)d_in[12]; const float* bt2  = (const float*)d_in[13];
    const float* Wav1 = (const float*)d_in[14]; const float* bav1 = (const float*)d_in[15];
    const float* Wav2 = (const float*)d_in[16]; const float* bav2 = (const float*)d_in[17];
    const float* Wg1  = (const float*)d_in[18]; const float* bg1  = (const float*)d_in[19];
    const float* Wg2  = (const float*)d_in[20]; const float* bg2  = (const float*)d_in[21];
    float* out = (float*)d_out;

    // ---- workspace carving (~57 MB) ----
    char* p = (char*)d_ws;
    auto carve = [&](size_t nbytes) -> void* {
        void* r = (void*)p; p += (nbytes + 255) & ~(size_t)255; return r;
    };
    float*          mean_cur = (float*)carve((size_t)NCHAIN * HDIM * 4);
    unsigned short* H1bf     = (unsigned short*)carve((size_t)NCHAIN * HDIM * 2);
    float*          Hav      = (float*)carve((size_t)NCHAIN * HDIM * 4);
    float*          NS       = (float*)carve((size_t)3 * NCHAIN * HDIM * 4);
    unsigned short* h_bf     = (unsigned short*)mean_cur;  // aliases region (33.55MB <= 36MB)
    unsigned short* WTt1  = (unsigned short*)carve((size_t)1024 * 2048 * 2);
    unsigned short* WTt2  = (unsigned short*)carve((size_t)1024 * 1024 * 2);
    unsigned short* WTav1 = (unsigned short*)carve((size_t)1024 * 2048 * 2);
    unsigned short* WTg1  = (unsigned short*)carve((size_t)1024 * 2048 * 2);
    unsigned short* WTg2  = (unsigned short*)carve((size_t)1024 * 1024 * 2);
    unsigned short* Wp1hi = (unsigned short*)carve((size_t)1024 * 1024 * 2);
    unsigned short* Wp1lo = (unsigned short*)carve((size_t)1024 * 1024 * 2);
    float*  rmean  = (float*)carve(BATCH * HDIM * 4);
    float*  T1     = (float*)carve(BATCH * HDIM * 4);
    float*  logits = (float*)carve(128 * 4);
    float*  wp2m   = (float*)carve(1040 * 4);
    double* fl64   = (double*)carve((size_t)BATCH * SEQ * 8);
    float*  fl32   = (float*)carve(BATCH * SEQ * 4);
    float*  wbuf   = (float*)carve(NCHAIN * 4);
    double* Wsumd  = (double*)carve(64 * 8);
    int*    sims   = (int*)carve(64 * 4);
    int*    idxj   = (int*)carve(3 * NCHAIN * 4);
    int*    vidx   = (int*)carve(NCHAIN * 4);

    // 1) weight transposes
    transpose_bf16<<<dim3(2048 / 32, 1024 / 32), 256, 0, stream>>>(Wt1, WTt1, 2048, 1024);
    transpose_bf16<<<dim3(1024 / 32, 1024 / 32), 256, 0, stream>>>(Wt2, WTt2, 1024, 1024);
    transpose_bf16<<<dim3(2048 / 32, 1024 / 32), 256, 0, stream>>>(Wav1, WTav1, 2048, 1024);
    transpose_bf16<<<dim3(2048 / 32, 1024 / 32), 256, 0, stream>>>(Wg1, WTg1, 2048, 1024);
    transpose_bf16<<<dim3(1024 / 32, 1024 / 32), 256, 0, stream>>>(Wg2, WTg2, 1024, 1024);
    transpose_split<<<dim3(1024 / 32, 1024 / 32), 256, 0, stream>>>(Wp1, Wp1hi, Wp1lo, 1024, 1024);
    // 2) wp2 means, root mean
    wp2mean_kernel<<<1025, 256, 0, stream>>>(Wp2, bp2, wp2m);
    rootmean_kernel<<<dim3(BATCH, HDIM / 256), 256, 0, stream>>>(root, rmean);
    // 3) controller (fp64) -> sims
    ctrl_fc1<<<64, 256, 0, stream>>>(root, Wsc1, bsc1, T1);
    ctrl_fc2<<<80, 256, 0, stream>>>(T1, Wsc2, bsc2, logits);
    sims_kernel<<<1, 64, 0, stream>>>(logits, sims);
    // 4) policy (bf16x3 MFMA) + fused focus logits
    hipMemsetAsync(fl64, 0, (size_t)BATCH * SEQ * 8, stream);
    policy_bf16x3<<<dim3(8, 128), 256, 0, stream>>>(root, Wp1hi, Wp1lo, bp1, wp2m, fl64);
    flbuild_kernel<<<BATCH * SEQ / 256, 256, 0, stream>>>(fl64, wp2m, amask, fl32);
    // 5) gumbel top-3 (partitionable threefry, unchanged)
    gumbel_kernel<<<NCHAIN, 256, 0, stream>>>(fl32, idxj, vidx);
    // 6) transitions (TM=64 tiles: 200 blocks)
    meaninit_kernel<<<NCHAIN * HDIM / 256, 256, 0, stream>>>(rmean, mean_cur);
    for (int j = 0; j < 3; j++) {
        gemm_bt<0, 64><<<dim3(8, 25), 256, 0, stream>>>(
            mean_cur, 1024, nullptr, root, 1024, idxj + j * NCHAIN, 1024,
            WTt1, bt1, nullptr, nullptr, H1bf, 1024, NCHAIN, 1024, 2048, 1);
        gemm_bt<1, 64><<<dim3(8, 25), 256, 0, stream>>>(
            H1bf, 1024, nullptr, nullptr, 0, nullptr, 1 << 30,
            WTt2, bt2, nullptr, NS + (size_t)j * NCHAIN * HDIM, nullptr,
            1024, NCHAIN, 1024, 1024, 0);
        meanupd_kernel<<<NCHAIN * HDIM / 256, 256, 0, stream>>>(
            NS + (size_t)j * NCHAIN * HDIM, root, idxj + j * NCHAIN, mean_cur);
    }
    // 7) action value -> w -> Wsum
    gemm_bt<0, 64><<<dim3(8, 25), 256, 0, stream>>>(
        rmean, 1024, vidx, mean_cur, 1024, nullptr, 1024,
        WTav1, bav1, nullptr, Hav, nullptr, 1024, NCHAIN, 1024, 2048, 1);
    valdot_kernel<<<NCHAIN, 256, 0, stream>>>(Hav, Wav2, bav2, wbuf);
    wsum_kernel<<<1, 64, 0, stream>>>(wbuf, sims, Wsumd);
    // 8) acc (in d_out): init + parallel corrections
    accinit_kernel<<<(BATCH * SEQ * HDIM) / 256, 256, 0, stream>>>(root, Wsumd, out);
    corrections_atomic<<<3 * NCHAIN, 256, 0, stream>>>(NS, root, wbuf, sims, idxj, out);
    // 9) aggregation
    gemm_bt<0, 128><<<dim3(8, 128), 256, 0, stream>>>(
        root, 1024, nullptr, out, 1024, nullptr, 1024,
        WTg1, bg1, nullptr, nullptr, h_bf, 1024, BATCH * SEQ, 1024, 2048, 1);
    gemm_bt<1, 128><<<dim3(8, 128), 256, 0, stream>>>(
        h_bf, 1024, nullptr, nullptr, 0, nullptr, 1 << 30,
        WTg2, bg2, root, out, nullptr, 1024, BATCH * SEQ, 1024, 1024, 0);
}

// Round 9
// 931.558 us; speedup vs baseline: 7.7539x; 1.0644x over previous
//
#include <hip/hip_runtime.h>
#include <hip/hip_bf16.h>
#include <cstdint>
#include <math.h>

// ---------------------------------------------------------------------------
// AdaptiveMCTSReasoner  B=16, S=1024, H=1024, MAX_SIMS=100, K_FOCUS=3
// Round 9: round 8 + XCD-aware bijective block swizzle (T1) on all big GEMMs.
// Round-8 profile: agg/policy dispatches FETCH 528MB @2.3TB/s, MfmaUtil 11%
// -> HBM-bound on A re-fetch across XCDs. Swizzle keeps the 8 col-blocks of
// each A row-panel on one XCD so its private L2 serves 7 of 8 reads.
// ---------------------------------------------------------------------------

#define SEQ 1024
#define BATCH 16
#define HDIM 1024
#define NSIM 100
#define NCHAIN (NSIM * BATCH)   // 1600
#define SHC (SEQ * HDIM)

typedef short bf16x8 __attribute__((ext_vector_type(8)));
typedef float f32x4 __attribute__((ext_vector_type(4)));
typedef float float4v __attribute__((ext_vector_type(4)));

__device__ __forceinline__ unsigned short f2bf(float f) {
    union { float f; uint32_t u; } c; c.f = f;
    uint32_t u = c.u;
    return (unsigned short)((u + 0x7FFFu + ((u >> 16) & 1u)) >> 16);   // RNE
}
__device__ __forceinline__ float bf2f(unsigned short h) {
    union { uint32_t u; float f; } c; c.u = ((uint32_t)h) << 16;
    return c.f;
}

__device__ __forceinline__ void gll16(const void* g, void* l) {
    __builtin_amdgcn_global_load_lds(
        (const __attribute__((address_space(1))) void*)g,
        (__attribute__((address_space(3))) void*)l, 16, 0, 0);
}

__device__ __forceinline__ float gelu32(float x) {
    return 0.5f * x * (1.0f + erff(x * 0.70710678f));
}

// XCD-aware bijective swizzle (requires nwg % 8 == 0; all our grids qualify)
__device__ __forceinline__ void swz_block(int& bx, int& by) {
    int gx = gridDim.x;
    int h = blockIdx.y * gx + blockIdx.x;
    int nwg = gx * gridDim.y;
    int l = (h & 7) * (nwg >> 3) + (h >> 3);
    bx = l % gx; by = l / gx;
}

// ------------------------------- threefry ----------------------------------
__device__ __forceinline__ uint32_t rotl32(uint32_t v, int r) {
    return (v << r) | (v >> (32 - r));
}

__device__ __forceinline__ void threefry(uint32_t k0, uint32_t k1,
                                         uint32_t c0, uint32_t c1,
                                         uint32_t& o0, uint32_t& o1) {
    uint32_t ks0 = k0, ks1 = k1, ks2 = k0 ^ k1 ^ 0x1BD11BDAu;
    uint32_t x0 = c0 + ks0, x1 = c1 + ks1;
#define TFR(r) { x0 += x1; x1 = rotl32(x1, r); x1 ^= x0; }
    TFR(13) TFR(15) TFR(26) TFR(6)   x0 += ks1; x1 += ks2 + 1u;
    TFR(17) TFR(29) TFR(16) TFR(24)  x0 += ks2; x1 += ks0 + 2u;
    TFR(13) TFR(15) TFR(26) TFR(6)   x0 += ks0; x1 += ks1 + 3u;
    TFR(17) TFR(29) TFR(16) TFR(24)  x0 += ks1; x1 += ks2 + 4u;
    TFR(13) TFR(15) TFR(26) TFR(6)   x0 += ks2; x1 += ks0 + 5u;
#undef TFR
    o0 = x0; o1 = x1;
}

__device__ __forceinline__ bool better(float va, int ia, float vb, int ib) {
    return (va > vb) || (va == vb && ia < ib);
}

// ----------------- weight transpose+convert: WT[n][k] = bf16(W[k][n]) ------
__global__ __launch_bounds__(256)
void transpose_bf16(const float* __restrict__ W, unsigned short* __restrict__ WT,
                    int K, int N) {
    __shared__ float t[32][33];
    int kb = blockIdx.x * 32, nb = blockIdx.y * 32;
    int tx = threadIdx.x & 31, ty4 = threadIdx.x >> 5;
#pragma unroll
    for (int p = 0; p < 4; ++p) {
        int ky = ty4 + p * 8;
        t[ky][tx] = W[(long)(kb + ky) * N + nb + tx];
    }
    __syncthreads();
#pragma unroll
    for (int p = 0; p < 4; ++p) {
        int ny = ty4 + p * 8;
        WT[(long)(nb + ny) * K + kb + tx] = f2bf(t[tx][ny]);
    }
}

// hi/lo split transpose for Wp1
__global__ __launch_bounds__(256)
void transpose_split(const float* __restrict__ W, unsigned short* __restrict__ Whi,
                     unsigned short* __restrict__ Wlo, int K, int N) {
    __shared__ float t[32][33];
    int kb = blockIdx.x * 32, nb = blockIdx.y * 32;
    int tx = threadIdx.x & 31, ty4 = threadIdx.x >> 5;
#pragma unroll
    for (int p = 0; p < 4; ++p) {
        int ky = ty4 + p * 8;
        t[ky][tx] = W[(long)(kb + ky) * N + nb + tx];
    }
    __syncthreads();
#pragma unroll
    for (int p = 0; p < 4; ++p) {
        int ny = ty4 + p * 8;
        float w = t[tx][ny];
        unsigned short h = f2bf(w);
        Whi[(long)(nb + ny) * K + kb + tx] = h;
        Wlo[(long)(nb + ny) * K + kb + tx] = f2bf(w - bf2f(h));
    }
}

// ------------------------- GEMM (bf16 MFMA, B^T weights) --------------------
// TM = tile rows (128 or 64). 4 waves as 2x2; wave tile (TM/2) x 64.
template<int ABF, int TM>
__global__ __launch_bounds__(256)
void gemm_bt(const void* __restrict__ Av1, long lda1, const int* __restrict__ a1rows,
             const void* __restrict__ Av2, long lda2, const int* __restrict__ a2rows,
             int K1,
             const unsigned short* __restrict__ WT,
             const float* __restrict__ bias,
             const float* __restrict__ Cadd,
             float* __restrict__ C,
             unsigned short* __restrict__ Cbf,
             long ldc, int M, int N, int K, int doGelu) {
    constexpr int MT = TM / 32;          // row-frags per wave
    constexpr int WROWS = TM / 2;
    __shared__ unsigned short As[TM * 64];
    __shared__ unsigned short Bs[128 * 64];
    __shared__ int r1s[TM], r2s[TM];
    int tid = threadIdx.x;
    int bx, by; swz_block(bx, by);
    int row0 = by * TM, col0 = bx * 128;
    if (tid < TM) {
        int gm = row0 + tid; if (gm >= M) gm = M - 1;
        r1s[tid] = a1rows ? a1rows[gm] : gm;
        r2s[tid] = a2rows ? a2rows[gm] : gm;
    }
    int wid = tid >> 6, lane = tid & 63;
    int wr = wid >> 1, wc = wid & 1, llo = lane & 15, lhi = lane >> 4;
    f32x4 acc[MT][4];
#pragma unroll
    for (int i = 0; i < MT; i++)
#pragma unroll
        for (int j = 0; j < 4; j++) acc[i][j] = (f32x4){0.f, 0.f, 0.f, 0.f};
    __syncthreads();

    char* AsB = (char*)As;
    char* BsB = (char*)Bs;
    for (int k0 = 0; k0 < K; k0 += 64) {
        // ---- B stage: gll, source chunk inverse-swizzled ----
#pragma unroll
        for (int i = 0; i < 4; ++i) {
            int q = tid + (i << 8);
            int r = q >> 3, cs = q & 7, c = cs ^ (r & 7);
            gll16(WT + (long)(col0 + r) * K + (k0 + (c << 3)), BsB + (q << 4));
        }
        // ---- A stage ----
        if (ABF) {
            const unsigned short* Ab = (const unsigned short*)Av1;
#pragma unroll
            for (int i = 0; i < MT; ++i) {
                int q = tid + (i << 8);
                int r = q >> 3, cs = q & 7, c = cs ^ (r & 7);
                gll16(Ab + (long)r1s[r] * lda1 + (k0 + (c << 3)), AsB + (q << 4));
            }
        } else {
            const float* A1f = (const float*)Av1;
            const float* A2f = (const float*)Av2;
            bool s1 = (k0 < K1);
#pragma unroll
            for (int i = 0; i < MT; ++i) {
                int q = tid + (i << 8);
                int r = q >> 3, c = q & 7;
                const float* src = s1 ? (A1f + (long)r1s[r] * lda1 + (k0 + (c << 3)))
                                      : (A2f + (long)r2s[r] * lda2 + (k0 - K1 + (c << 3)));
                float4v v0 = *(const float4v*)src;
                float4v v1 = *(const float4v*)(src + 4);
                bf16x8 s;
                s[0] = (short)f2bf(v0[0]); s[1] = (short)f2bf(v0[1]);
                s[2] = (short)f2bf(v0[2]); s[3] = (short)f2bf(v0[3]);
                s[4] = (short)f2bf(v1[0]); s[5] = (short)f2bf(v1[1]);
                s[6] = (short)f2bf(v1[2]); s[7] = (short)f2bf(v1[3]);
                *(bf16x8*)(AsB + ((r << 7) + ((c ^ (r & 7)) << 4))) = s;
            }
        }
        __syncthreads();
#pragma unroll
        for (int ks = 0; ks < 2; ++ks) {
            bf16x8 af[MT], bfv[4];
#pragma unroll
            for (int mt = 0; mt < MT; ++mt) {
                int r = wr * WROWS + mt * 16 + llo;
                af[mt] = *(const bf16x8*)(AsB + ((r << 7) + ((((ks << 2) | lhi) ^ (r & 7)) << 4)));
            }
#pragma unroll
            for (int nt = 0; nt < 4; ++nt) {
                int r = wc * 64 + nt * 16 + llo;
                bfv[nt] = *(const bf16x8*)(BsB + ((r << 7) + ((((ks << 2) | lhi) ^ (r & 7)) << 4)));
            }
#pragma unroll
            for (int mt = 0; mt < MT; ++mt)
#pragma unroll
                for (int nt = 0; nt < 4; ++nt)
                    acc[mt][nt] = __builtin_amdgcn_mfma_f32_16x16x32_bf16(
                        af[mt], bfv[nt], acc[mt][nt], 0, 0, 0);
        }
        __syncthreads();
    }
    // epilogue: C/D col=lane&15, row=(lane>>4)*4+reg  [m89-verified]
#pragma unroll
    for (int mt = 0; mt < MT; ++mt) {
#pragma unroll
        for (int nt = 0; nt < 4; ++nt) {
            int gn = col0 + wc * 64 + nt * 16 + llo;
#pragma unroll
            for (int r = 0; r < 4; ++r) {
                int gm = row0 + wr * WROWS + mt * 16 + lhi * 4 + r;
                if (gm >= M) continue;
                float v = acc[mt][nt][r] + bias[gn];
                if (doGelu) v = gelu32(v);
                if (Cadd) v += Cadd[(long)gm * ldc + gn];
                if (C)   C[(long)gm * ldc + gn] = v;
                if (Cbf) Cbf[(long)gm * ldc + gn] = f2bf(v);
            }
        }
    }
}

// ---------------- policy: bf16x3 MFMA GEMM with fused focus-logit dot -------
__global__ __launch_bounds__(256)
void policy_bf16x3(const float* __restrict__ root,
                   const unsigned short* __restrict__ Whi,
                   const unsigned short* __restrict__ Wlo,
                   const float* __restrict__ bp1, const float* __restrict__ wp2m,
                   double* __restrict__ fl64) {
    __shared__ unsigned short Ahi[128 * 64], Alo[128 * 64];
    __shared__ unsigned short Bhi[128 * 64], Blo[128 * 64];
    int tid = threadIdx.x;
    int bx, by; swz_block(bx, by);
    int row0 = by * 128, col0 = bx * 128;
    int wid = tid >> 6, lane = tid & 63;
    int wr = wid >> 1, wc = wid & 1, llo = lane & 15, lhi = lane >> 4;
    f32x4 acc[4][4];
#pragma unroll
    for (int i = 0; i < 4; i++)
#pragma unroll
        for (int j = 0; j < 4; j++) acc[i][j] = (f32x4){0.f, 0.f, 0.f, 0.f};

    char* AhB = (char*)Ahi; char* AlB = (char*)Alo;
    char* BhB = (char*)Bhi; char* BlB = (char*)Blo;
    for (int k0 = 0; k0 < 1024; k0 += 64) {
        // B stage: both splits via gll, inverse-swizzled source
#pragma unroll
        for (int i = 0; i < 4; ++i) {
            int q = tid + (i << 8);
            int r = q >> 3, cs = q & 7, c = cs ^ (r & 7);
            long off = (long)(col0 + r) * 1024 + (k0 + (c << 3));
            gll16(Whi + off, BhB + (q << 4));
            gll16(Wlo + off, BlB + (q << 4));
        }
        // A stage: read fp32, split hi/lo, swizzled ds_write
#pragma unroll
        for (int i = 0; i < 4; ++i) {
            int q = tid + (i << 8);
            int r = q >> 3, c = q & 7;
            const float* src = root + (long)(row0 + r) * 1024 + (k0 + (c << 3));
            float4v v0 = *(const float4v*)src;
            float4v v1 = *(const float4v*)(src + 4);
            bf16x8 sh, sl;
#pragma unroll
            for (int e = 0; e < 4; ++e) {
                unsigned short h0 = f2bf(v0[e]);
                sh[e] = (short)h0; sl[e] = (short)f2bf(v0[e] - bf2f(h0));
                unsigned short h1 = f2bf(v1[e]);
                sh[e + 4] = (short)h1; sl[e + 4] = (short)f2bf(v1[e] - bf2f(h1));
            }
            int off = (r << 7) + ((c ^ (r & 7)) << 4);
            *(bf16x8*)(AhB + off) = sh;
            *(bf16x8*)(AlB + off) = sl;
        }
        __syncthreads();
#pragma unroll
        for (int ks = 0; ks < 2; ++ks) {
            bf16x8 ah[4], al[4], bh[4], bl[4];
#pragma unroll
            for (int mt = 0; mt < 4; ++mt) {
                int r = wr * 64 + mt * 16 + llo;
                int off = (r << 7) + ((((ks << 2) | lhi) ^ (r & 7)) << 4);
                ah[mt] = *(const bf16x8*)(AhB + off);
                al[mt] = *(const bf16x8*)(AlB + off);
            }
#pragma unroll
            for (int nt = 0; nt < 4; ++nt) {
                int r = wc * 64 + nt * 16 + llo;
                int off = (r << 7) + ((((ks << 2) | lhi) ^ (r & 7)) << 4);
                bh[nt] = *(const bf16x8*)(BhB + off);
                bl[nt] = *(const bf16x8*)(BlB + off);
            }
#pragma unroll
            for (int mt = 0; mt < 4; ++mt)
#pragma unroll
                for (int nt = 0; nt < 4; ++nt) {
                    acc[mt][nt] = __builtin_amdgcn_mfma_f32_16x16x32_bf16(
                        ah[mt], bh[nt], acc[mt][nt], 0, 0, 0);
                    acc[mt][nt] = __builtin_amdgcn_mfma_f32_16x16x32_bf16(
                        ah[mt], bl[nt], acc[mt][nt], 0, 0, 0);
                    acc[mt][nt] = __builtin_amdgcn_mfma_f32_16x16x32_bf16(
                        al[mt], bh[nt], acc[mt][nt], 0, 0, 0);
                }
        }
        __syncthreads();
    }
    // epilogue: per-lane row partials (double), reduce over llo, atomicAdd
#pragma unroll
    for (int mt = 0; mt < 4; ++mt) {
        double part[4] = {0.0, 0.0, 0.0, 0.0};
#pragma unroll
        for (int nt = 0; nt < 4; ++nt) {
            int gn = col0 + wc * 64 + nt * 16 + llo;
            float b = bp1[gn], wn = wp2m[gn];
#pragma unroll
            for (int r = 0; r < 4; ++r) {
                float x = acc[mt][nt][r] + b;
                part[r] += (double)gelu32(x) * (double)wn;
            }
        }
#pragma unroll
        for (int r = 0; r < 4; ++r) {
            double v = part[r];
            v += __shfl_xor(v, 1);
            v += __shfl_xor(v, 2);
            v += __shfl_xor(v, 4);
            v += __shfl_xor(v, 8);
            if (llo == 0)
                atomicAdd(&fl64[row0 + wr * 64 + mt * 16 + lhi * 4 + r], v);
        }
    }
}

__global__ void flbuild_kernel(const double* __restrict__ fl64,
                               const float* __restrict__ wp2m,
                               const int* __restrict__ amask,
                               float* __restrict__ fl32) {
    int m = blockIdx.x * 256 + threadIdx.x;
    fl32[m] = (amask[m] == 0) ? -1e9f : (float)(fl64[m] + (double)wp2m[1024]);
}

// --------------------------- small kernels ---------------------------------
__global__ void wp2mean_kernel(const float* __restrict__ Wp2,
                               const float* __restrict__ bp2,
                               float* __restrict__ outv) {
    __shared__ double sb[256];
    int r = blockIdx.x, tid = threadIdx.x;
    const float* src = (r < 1024) ? (Wp2 + (size_t)r * 1024) : bp2;
    double s = 0.0;
    for (int k = tid; k < 1024; k += 256) s += (double)src[k];
    sb[tid] = s; __syncthreads();
    for (int off = 128; off > 0; off >>= 1) {
        if (tid < off) sb[tid] += sb[tid + off];
        __syncthreads();
    }
    if (tid == 0) outv[r] = (float)(sb[0] * (1.0 / 1024.0));
}

__global__ void rootmean_kernel(const float* __restrict__ root, float* __restrict__ rmean) {
    int b = blockIdx.x;
    int h = blockIdx.y * 256 + threadIdx.x;
    const float* base = root + (size_t)b * SHC + h;
    double s = 0.0;
    for (int ss = 0; ss < SEQ; ss++) s += (double)base[(size_t)ss * HDIM];
    rmean[b * HDIM + h] = (float)(s * (1.0 / 1024.0));
}

__global__ __launch_bounds__(256)
void ctrl_fc1(const float* __restrict__ root, const float* __restrict__ W,
              const float* __restrict__ b1, float* __restrict__ T1) {
    __shared__ double red[16][17];
    int ni = threadIdx.x & 15, kt = threadIdx.x >> 4;
    int n = blockIdx.x * 16 + ni;
    double accb[16];
#pragma unroll
    for (int bb = 0; bb < 16; ++bb) accb[bb] = 0.0;
    for (int k = kt * 64; k < kt * 64 + 64; ++k) {
        double w = (double)W[(long)k * 1024 + n];
#pragma unroll
        for (int bb = 0; bb < 16; ++bb)
            accb[bb] = fma((double)root[(long)bb * SHC + k], w, accb[bb]);
    }
    for (int bb = 0; bb < 16; ++bb) {
        red[kt][ni] = accb[bb];
        __syncthreads();
        if (kt == 0) {
            double s = 0.0;
            for (int q = 0; q < 16; ++q) s += red[q][ni];
            double x = s + (double)b1[n];
            T1[bb * 1024 + n] = (float)(0.5 * x * (1.0 + erf(x * 0.70710678118654752440)));
        }
        __syncthreads();
    }
}

__global__ void ctrl_fc2(const float* __restrict__ T1, const float* __restrict__ W2,
                         const float* __restrict__ b2, float* __restrict__ logits) {
    __shared__ double sb[256];
    int bn = blockIdx.x;
    int b = bn / 5, n = bn % 5;
    double s = 0.0;
    for (int k = threadIdx.x; k < 1024; k += 256)
        s += (double)T1[b * 1024 + k] * (double)W2[k * 5 + n];
    sb[threadIdx.x] = s; __syncthreads();
    for (int off = 128; off > 0; off >>= 1) {
        if (threadIdx.x < off) sb[threadIdx.x] += sb[threadIdx.x + off];
        __syncthreads();
    }
    if (threadIdx.x == 0) logits[b * 5 + n] = (float)(sb[0] + (double)b2[n]);
}

__global__ void sims_kernel(const float* __restrict__ logits, int* __restrict__ sims) {
    int b = threadIdx.x;
    if (b >= BATCH) return;
    float best = logits[b * 5 + 0]; int biv = 0;
    for (int i = 1; i < 5; i++) {
        float v = logits[b * 5 + i];
        if (v > best) { best = v; biv = i; }
    }
    const int opt[5] = {10, 25, 50, 75, 100};
    sims[b] = opt[biv];
}

// Per (t,b): JAX PARTITIONABLE threefry (byte-identical to rounds 5-8)
__global__ void gumbel_kernel(const float* __restrict__ fl,
                              int* __restrict__ idxj, int* __restrict__ vidx) {
    __shared__ float sv[256][3];
    __shared__ int   si[256][3];
    int blk = blockIdx.x;           // c = t*16+b
    int t = blk >> 4, b = blk & 15;
    uint32_t kk0, kk1;
    threefry(0u, 42u, 0u, (uint32_t)t, kk0, kk1);   // fold_in(key(42), t)
    int tid = threadIdx.x;
    float bv[3] = {-INFINITY, -INFINITY, -INFINITY};
    int   bi[3] = {0x7FFFFFFF, 0x7FFFFFFF, 0x7FFFFFFF};
    for (int s = tid; s < SEQ; s += 256) {
        uint32_t m = (uint32_t)(b * SEQ + s);
        uint32_t y0, y1;
        threefry(kk0, kk1, 0u, m, y0, y1);
        uint32_t bits = y0 ^ y1;
        float f = __uint_as_float((bits >> 9) | 0x3F800000u) - 1.0f;
        float u = fmaxf(1.17549435e-38f, f);
        float l1 = (float)log((double)u);
        float l2 = (float)log(-(double)l1);
        float g  = -l2;
        float val = fl[b * SEQ + s] + g;
        if (better(val, s, bv[2], bi[2])) {
            bv[2] = val; bi[2] = s;
            if (better(bv[2], bi[2], bv[1], bi[1])) {
                float tv = bv[1]; int ti = bi[1];
                bv[1] = bv[2]; bi[1] = bi[2]; bv[2] = tv; bi[2] = ti;
            }
            if (better(bv[1], bi[1], bv[0], bi[0])) {
                float tv = bv[0]; int ti = bi[0];
                bv[0] = bv[1]; bi[0] = bi[1]; bv[1] = tv; bi[1] = ti;
            }
        }
    }
    sv[tid][0] = bv[0]; sv[tid][1] = bv[1]; sv[tid][2] = bv[2];
    si[tid][0] = bi[0]; si[tid][1] = bi[1]; si[tid][2] = bi[2];
    __syncthreads();
    for (int off = 128; off > 0; off >>= 1) {
        if (tid < off) {
            float av[3] = {sv[tid][0], sv[tid][1], sv[tid][2]};
            int   ai[3] = {si[tid][0], si[tid][1], si[tid][2]};
            float cv[3] = {sv[tid + off][0], sv[tid + off][1], sv[tid + off][2]};
            int   ci[3] = {si[tid + off][0], si[tid + off][1], si[tid + off][2]};
            float rv[3]; int ri[3]; int pa = 0, pb = 0;
#pragma unroll
            for (int r = 0; r < 3; r++) {
                if (better(av[pa], ai[pa], cv[pb], ci[pb])) { rv[r] = av[pa]; ri[r] = ai[pa]; pa++; }
                else                                        { rv[r] = cv[pb]; ri[r] = ci[pb]; pb++; }
            }
            sv[tid][0] = rv[0]; sv[tid][1] = rv[1]; sv[tid][2] = rv[2];
            si[tid][0] = ri[0]; si[tid][1] = ri[1]; si[tid][2] = ri[2];
        }
        __syncthreads();
    }
    if (tid == 0) {
        idxj[0 * NCHAIN + blk] = b * SEQ + si[0][0];
        idxj[1 * NCHAIN + blk] = b * SEQ + si[0][1];
        idxj[2 * NCHAIN + blk] = b * SEQ + si[0][2];
        vidx[blk] = b;
    }
}

__global__ void meaninit_kernel(const float* __restrict__ rmean, float* __restrict__ mean_cur) {
    int e = blockIdx.x * 256 + threadIdx.x;
    int c = e >> 10, hh = e & 1023;
    mean_cur[e] = rmean[(c & 15) * HDIM + hh];
}

__global__ void meanupd_kernel(const float* __restrict__ NSj, const float* __restrict__ root,
                               const int* __restrict__ idx, float* __restrict__ mean_cur) {
    int e = blockIdx.x * 256 + threadIdx.x;
    int c = e >> 10, hh = e & 1023;
    int r = idx[c];
    double m = (double)mean_cur[e] +
               ((double)NSj[e] - (double)root[(size_t)r * HDIM + hh]) * (1.0 / 1024.0);
    mean_cur[e] = (float)m;
}

__global__ void valdot_kernel(const float* __restrict__ HV, const float* __restrict__ Wav2,
                              const float* __restrict__ bav2, float* __restrict__ w) {
    __shared__ double sb[256];
    int c = blockIdx.x, tid = threadIdx.x;
    double s = 0.0;
    for (int k = tid; k < HDIM; k += 256) s += (double)HV[(size_t)c * HDIM + k] * (double)Wav2[k];
    sb[tid] = s; __syncthreads();
    for (int off = 128; off > 0; off >>= 1) {
        if (tid < off) sb[tid] += sb[tid + off];
        __syncthreads();
    }
    if (tid == 0) {
        double v = sb[0] + (double)bav2[0];
        w[c] = (float)(1.0 / (1.0 + exp(-v)));
    }
}

__global__ void wsum_kernel(const float* __restrict__ w, const int* __restrict__ sims,
                            double* __restrict__ Wsum) {
    int b = threadIdx.x;
    if (b >= BATCH) return;
    int sb = sims[b];
    double s = 0.0;
    for (int t = 0; t < sb; t++) s += (double)w[t * BATCH + b];
    Wsum[b] = s;
}

__global__ void accinit_kernel(const float* __restrict__ root, const double* __restrict__ Wsum,
                               float* __restrict__ acc) {
    size_t e = (size_t)blockIdx.x * 256 + threadIdx.x;
    int b = (int)(e >> 20);
    acc[e] = (float)((1.0 + Wsum[b]) * (double)root[e]);
}

__global__ __launch_bounds__(256)
void corrections_atomic(const float* __restrict__ NS, const float* __restrict__ root,
                        const float* __restrict__ w, const int* __restrict__ sims,
                        const int* __restrict__ idxj, float* __restrict__ acc) {
    int blk = blockIdx.x;                // 0..4799
    int j = blk / NCHAIN, c = blk % NCHAIN;
    int b = c & 15, t = c >> 4;
    if (t >= sims[b]) return;
    float wv = w[c];
    int row = idxj[j * NCHAIN + c];
    const float* ns = NS + ((long)j * NCHAIN + c) * 1024;
    const float* rt = root + (long)row * 1024;
    float* ac = acc + (long)row * 1024;
    for (int h = threadIdx.x; h < 1024; h += 256)
        atomicAdd(&ac[h], wv * (ns[h] - rt[h]));
}

// ------------------------------- launch ------------------------------------
extern "C" void kernel_launch(void* const* d_in, const int* in_sizes, int n_in,
                              void* d_out, int out_size, void* d_ws, size_t ws_size,
                              hipStream_t stream) {
    (void)in_sizes; (void)n_in; (void)out_size; (void)ws_size;
    const float* root = (const float*)d_in[0];
    const int*   amask = (const int*)d_in[1];
    const float* Wsc1 = (const float*)d_in[2];  const float* bsc1 = (const float*)d_in[3];
    const float* Wsc2 = (const float*)d_in[4];  const float* bsc2 = (const float*)d_in[5];
    const float* Wp1  = (const float*)d_in[6];  const float* bp1  = (const float*)d_in[7];
    const float* Wp2  = (const float*)d_in[8];  const float* bp2  = (const float*)d_in[9];
    const float* Wt1  = (const float*)d_in[10]; const float* bt1  = (const float*)d_in[11];
    const float* Wt2  = (const float*)d_in[12]; const float* bt2  = (const float*)d_in[13];
    const float* Wav1 = (const float*)d_in[14]; const float* bav1 = (const float*)d_in[15];
    const float* Wav2 = (const float*)d_in[16]; const float* bav2 = (const float*)d_in[17];
    const float* Wg1  = (const float*)d_in[18]; const float* bg1  = (const float*)d_in[19];
    const float* Wg2  = (const float*)d_in[20]; const float* bg2  = (const float*)d_in[21];
    float* out = (float*)d_out;

    // ---- workspace carving (~57 MB) ----
    char* p = (char*)d_ws;
    auto carve = [&](size_t nbytes) -> void* {
        void* r = (void*)p; p += (nbytes + 255) & ~(size_t)255; return r;
    };
    float*          mean_cur = (float*)carve((size_t)NCHAIN * HDIM * 4);
    unsigned short* H1bf     = (unsigned short*)carve((size_t)NCHAIN * HDIM * 2);
    float*          Hav      = (float*)carve((size_t)NCHAIN * HDIM * 4);
    float*          NS       = (float*)carve((size_t)3 * NCHAIN * HDIM * 4);
    unsigned short* h_bf     = (unsigned short*)mean_cur;  // aliases region (33.55MB <= 36MB)
    unsigned short* WTt1  = (unsigned short*)carve((size_t)1024 * 2048 * 2);
    unsigned short* WTt2  = (unsigned short*)carve((size_t)1024 * 1024 * 2);
    unsigned short* WTav1 = (unsigned short*)carve((size_t)1024 * 2048 * 2);
    unsigned short* WTg1  = (unsigned short*)carve((size_t)1024 * 2048 * 2);
    unsigned short* WTg2  = (unsigned short*)carve((size_t)1024 * 1024 * 2);
    unsigned short* Wp1hi = (unsigned short*)carve((size_t)1024 * 1024 * 2);
    unsigned short* Wp1lo = (unsigned short*)carve((size_t)1024 * 1024 * 2);
    float*  rmean  = (float*)carve(BATCH * HDIM * 4);
    float*  T1     = (float*)carve(BATCH * HDIM * 4);
    float*  logits = (float*)carve(128 * 4);
    float*  wp2m   = (float*)carve(1040 * 4);
    double* fl64   = (double*)carve((size_t)BATCH * SEQ * 8);
    float*  fl32   = (float*)carve(BATCH * SEQ * 4);
    float*  wbuf   = (float*)carve(NCHAIN * 4);
    double* Wsumd  = (double*)carve(64 * 8);
    int*    sims   = (int*)carve(64 * 4);
    int*    idxj   = (int*)carve(3 * NCHAIN * 4);
    int*    vidx   = (int*)carve(NCHAIN * 4);

    // 1) weight transposes
    transpose_bf16<<<dim3(2048 / 32, 1024 / 32), 256, 0, stream>>>(Wt1, WTt1, 2048, 1024);
    transpose_bf16<<<dim3(1024 / 32, 1024 / 32), 256, 0, stream>>>(Wt2, WTt2, 1024, 1024);
    transpose_bf16<<<dim3(2048 / 32, 1024 / 32), 256, 0, stream>>>(Wav1, WTav1, 2048, 1024);
    transpose_bf16<<<dim3(2048 / 32, 1024 / 32), 256, 0, stream>>>(Wg1, WTg1, 2048, 1024);
    transpose_bf16<<<dim3(1024 / 32, 1024 / 32), 256, 0, stream>>>(Wg2, WTg2, 1024, 1024);
    transpose_split<<<dim3(1024 / 32, 1024 / 32), 256, 0, stream>>>(Wp1, Wp1hi, Wp1lo, 1024, 1024);
    // 2) wp2 means, root mean
    wp2mean_kernel<<<1025, 256, 0, stream>>>(Wp2, bp2, wp2m);
    rootmean_kernel<<<dim3(BATCH, HDIM / 256), 256, 0, stream>>>(root, rmean);
    // 3) controller (fp64) -> sims
    ctrl_fc1<<<64, 256, 0, stream>>>(root, Wsc1, bsc1, T1);
    ctrl_fc2<<<80, 256, 0, stream>>>(T1, Wsc2, bsc2, logits);
    sims_kernel<<<1, 64, 0, stream>>>(logits, sims);
    // 4) policy (bf16x3 MFMA, swizzled) + fused focus logits
    hipMemsetAsync(fl64, 0, (size_t)BATCH * SEQ * 8, stream);
    policy_bf16x3<<<dim3(8, 128), 256, 0, stream>>>(root, Wp1hi, Wp1lo, bp1, wp2m, fl64);
    flbuild_kernel<<<BATCH * SEQ / 256, 256, 0, stream>>>(fl64, wp2m, amask, fl32);
    // 5) gumbel top-3 (partitionable threefry, unchanged)
    gumbel_kernel<<<NCHAIN, 256, 0, stream>>>(fl32, idxj, vidx);
    // 6) transitions (TM=64 tiles, swizzled)
    meaninit_kernel<<<NCHAIN * HDIM / 256, 256, 0, stream>>>(rmean, mean_cur);
    for (int j = 0; j < 3; j++) {
        gemm_bt<0, 64><<<dim3(8, 25), 256, 0, stream>>>(
            mean_cur, 1024, nullptr, root, 1024, idxj + j * NCHAIN, 1024,
            WTt1, bt1, nullptr, nullptr, H1bf, 1024, NCHAIN, 1024, 2048, 1);
        gemm_bt<1, 64><<<dim3(8, 25), 256, 0, stream>>>(
            H1bf, 1024, nullptr, nullptr, 0, nullptr, 1 << 30,
            WTt2, bt2, nullptr, NS + (size_t)j * NCHAIN * HDIM, nullptr,
            1024, NCHAIN, 1024, 1024, 0);
        meanupd_kernel<<<NCHAIN * HDIM / 256, 256, 0, stream>>>(
            NS + (size_t)j * NCHAIN * HDIM, root, idxj + j * NCHAIN, mean_cur);
    }
    // 7) action value -> w -> Wsum
    gemm_bt<0, 64><<<dim3(8, 25), 256, 0, stream>>>(
        rmean, 1024, vidx, mean_cur, 1024, nullptr, 1024,
        WTav1, bav1, nullptr, Hav, nullptr, 1024, NCHAIN, 1024, 2048, 1);
    valdot_kernel<<<NCHAIN, 256, 0, stream>>>(Hav, Wav2, bav2, wbuf);
    wsum_kernel<<<1, 64, 0, stream>>>(wbuf, sims, Wsumd);
    // 8) acc (in d_out): init + parallel corrections
    accinit_kernel<<<(BATCH * SEQ * HDIM) / 256, 256, 0, stream>>>(root, Wsumd, out);
    corrections_atomic<<<3 * NCHAIN, 256, 0, stream>>>(NS, root, wbuf, sims, idxj, out);
    // 9) aggregation (swizzled)
    gemm_bt<0, 128><<<dim3(8, 128), 256, 0, stream>>>(
        root, 1024, nullptr, out, 1024, nullptr, 1024,
        WTg1, bg1, nullptr, nullptr, h_bf, 1024, BATCH * SEQ, 1024, 2048, 1);
    gemm_bt<1, 128><<<dim3(8, 128), 256, 0, stream>>>(
        h_bf, 1024, nullptr, nullptr, 0, nullptr, 1 << 30,
        WTg2, bg2, root, out, nullptr, 1024, BATCH * SEQ, 1024, 1024, 0);
}